// Round 3
// baseline (1002.432 us; speedup 1.0000x reference)
//
#include <hip/hip_runtime.h>
#include <cstdint>
#include <cstddef>

#define NN 100000
#define NE 1600000
#define SCAN_BLOCKS ((NN + 1023) / 1024)   // 98
#define NB ((NN + 127) / 128)              // 782 dst-buckets of 128 nodes
#define BCAP 4096                          // mean fill 2046; 4096 is >40 sigma slack

__device__ __forceinline__ float4 f4_fma(float s, float4 a, float4 acc) {
    acc.x += s * a.x; acc.y += s * a.y; acc.z += s * a.z; acc.w += s * a.w;
    return acc;
}
__device__ __forceinline__ float4 f4_add(float4 a, float4 b) {
    return make_float4(a.x + b.x, a.y + b.y, a.z + b.z, a.w + b.w);
}

// Detect edge_index storage: int64 (odd 32-bit words all zero, values < 2^31)
// vs int32 (odd words are random node ids).
__global__ void detect_flag_kernel(const int* __restrict__ idx, int* __restrict__ flag) {
    __shared__ int cnt;
    if (threadIdx.x == 0) cnt = 0;
    __syncthreads();
    if (idx[2 * threadIdx.x + 1] == 0) atomicAdd(&cnt, 1);
    __syncthreads();
    if (threadIdx.x == 0) *flag = (cnt == (int)blockDim.x) ? 1 : 0;
}

// Pass 1: scatter edges into coarse dst-buckets as packed (src<<7 | dst&127).
// Appends to a bucket are temporally clustered -> dense 64B-line utilization.
__global__ void bucket_kernel(const void* __restrict__ idx, const int* __restrict__ flag,
                              int* __restrict__ bcnt, int* __restrict__ buckets) {
    int e = blockIdx.x * blockDim.x + threadIdx.x;
    if (e >= NE) return;
    int s_, d_;
    if (*flag) {
        const long long* p = (const long long*)idx;
        s_ = (int)p[e]; d_ = (int)p[NE + e];
    } else {
        const int* p = (const int*)idx;
        s_ = p[e]; d_ = p[NE + e];
    }
    int b = d_ >> 7;
    int pos = atomicAdd(&bcnt[b], 1);
    if (pos < BCAP) buckets[(size_t)b * BCAP + pos] = (s_ << 7) | (d_ & 127);
}

// Pass 2a: per-bucket LDS histogram -> deg (zero global atomics).
__global__ __launch_bounds__(256) void hist_kernel(const int* __restrict__ bcnt,
                                                   const int* __restrict__ buckets,
                                                   int* __restrict__ deg) {
    __shared__ int cnt[128];
    int t = threadIdx.x, b = blockIdx.x;
    if (t < 128) cnt[t] = 0;
    __syncthreads();
    int n = bcnt[b]; if (n > BCAP) n = BCAP;
    for (int i = t; i < n; i += 256) atomicAdd(&cnt[buckets[(size_t)b * BCAP + i] & 127], 1);
    __syncthreads();
    int node = b * 128 + t;
    if (t < 128 && node < NN) deg[node] = cnt[t];
}

__global__ void dinv_kernel(const int* __restrict__ deg, float* __restrict__ dinv) {
    int n = blockIdx.x * blockDim.x + threadIdx.x;
    if (n < NN) dinv[n] = rsqrtf((float)(deg[n] + 1));  // +1 self loop
}

// Hierarchical scan, pass 1: per-1024-chunk sums.
__global__ __launch_bounds__(256) void scanA_kernel(const int* __restrict__ deg,
                                                    int* __restrict__ blocksum) {
    __shared__ int red[256];
    int t = threadIdx.x;
    int base = blockIdx.x * 1024 + t * 4;
    int s = 0;
#pragma unroll
    for (int j = 0; j < 4; j++) { int i = base + j; if (i < NN) s += deg[i]; }
    red[t] = s;
    __syncthreads();
    for (int off = 128; off > 0; off >>= 1) {
        if (t < off) red[t] += red[t + off];
        __syncthreads();
    }
    if (t == 0) blocksum[blockIdx.x] = red[0];
}

// Scan pass 2: per-chunk exclusive scan + chunk offset -> row_start.
__global__ __launch_bounds__(256) void scanC_kernel(const int* __restrict__ deg,
                                                    const int* __restrict__ blocksum,
                                                    int* __restrict__ row_start) {
    __shared__ int lds[256];
    __shared__ int boff_s;
    int t = threadIdx.x;
    int b = blockIdx.x;
    lds[t] = (t < b && t < SCAN_BLOCKS) ? blocksum[t] : 0;
    __syncthreads();
    for (int off = 128; off > 0; off >>= 1) {
        if (t < off) lds[t] += lds[t + off];
        __syncthreads();
    }
    if (t == 0) boff_s = lds[0];
    __syncthreads();
    int boff = boff_s;

    int base = b * 1024 + t * 4;
    int d[4]; int s = 0;
#pragma unroll
    for (int j = 0; j < 4; j++) { int i = base + j; d[j] = (i < NN) ? deg[i] : 0; s += d[j]; }
    __syncthreads();
    lds[t] = s;
    __syncthreads();
    for (int off = 1; off < 256; off <<= 1) {
        int u = (t >= off) ? lds[t - off] : 0;
        __syncthreads();
        lds[t] += u;
        __syncthreads();
    }
    int offr = boff + ((t == 0) ? 0 : lds[t - 1]);
#pragma unroll
    for (int j = 0; j < 4; j++) {
        int i = base + j;
        if (i < NN) { row_start[i] = offr; offr += d[j]; }
    }
    if (b == 0 && t == 0) row_start[NN] = NE;
}

// Pass 2b: per-bucket scatter into CSR via LDS cursors; each block's writes
// are confined to an ~8KB window -> dense lines.
__global__ __launch_bounds__(256) void csrfill_kernel(const int* __restrict__ bcnt,
                                                      const int* __restrict__ buckets,
                                                      const int* __restrict__ row_start,
                                                      int* __restrict__ csr) {
    __shared__ int cur[128];
    int t = threadIdx.x, b = blockIdx.x;
    int node = b * 128 + t;
    if (t < 128) cur[t] = (node < NN) ? row_start[node] : 0;
    __syncthreads();
    int n = bcnt[b]; if (n > BCAP) n = BCAP;
    for (int i = t; i < n; i += 256) {
        int v = buckets[(size_t)b * BCAP + i];
        int pos = atomicAdd(&cur[v & 127], 1);
        csr[pos] = v >> 7;
    }
}

// H[N,F] = dinv[r] * (X[N,128] @ W[128,F]).  fp32 vector GEMM, W in LDS.
template <int F>
__global__ __launch_bounds__(256) void gemm_kernel(const float* __restrict__ X,
                                                   const float* __restrict__ W,
                                                   const float* __restrict__ dinv,
                                                   float* __restrict__ H, int N) {
    constexpr int K = 128;
    constexpr int CQ = F / 4;
    constexpr int RS = 256 / CQ;
    constexpr int ROWS = RS * 4;
    __shared__ float Wlds[K * F];
    for (int i = threadIdx.x; i < K * F / 4; i += 256)
        ((float4*)Wlds)[i] = ((const float4*)W)[i];
    __syncthreads();

    int c = (threadIdx.x % CQ) * 4;
    int r0 = blockIdx.x * ROWS + (threadIdx.x / CQ) * 4;
    float4 acc[4];
#pragma unroll
    for (int i = 0; i < 4; i++) acc[i] = make_float4(0.f, 0.f, 0.f, 0.f);

    for (int k = 0; k < K; k += 4) {
        float4 xv[4];
#pragma unroll
        for (int i = 0; i < 4; i++) {
            int rr = r0 + i; if (rr >= N) rr = N - 1;
            xv[i] = *(const float4*)&X[(size_t)rr * K + k];
        }
#pragma unroll
        for (int j = 0; j < 4; j++) {
            float4 wv = *(const float4*)&Wlds[(k + j) * F + c];
#pragma unroll
            for (int i = 0; i < 4; i++) {
                float xk = ((const float*)&xv[i])[j];
                acc[i] = f4_fma(xk, wv, acc[i]);
            }
        }
    }
#pragma unroll
    for (int i = 0; i < 4; i++) {
        int rr = r0 + i;
        if (rr < N) {
            float dv = dinv[rr];
            float4 o = make_float4(dv * acc[i].x, dv * acc[i].y, dv * acc[i].z, dv * acc[i].w);
            *(float4*)&H[(size_t)rr * F + c] = o;
        }
    }
}

// Hs is pre-scaled by dinv[row].  OUT[n] = (relu?)( b + dn * (Hs[n] + sum_e Hs[src]) )
template <int F, bool RELU>
__global__ __launch_bounds__(256) void agg_kernel(const float* __restrict__ Hs,
                                                  const int* __restrict__ rs,
                                                  const int* __restrict__ csr,
                                                  const float* __restrict__ dinv,
                                                  const float* __restrict__ bias,
                                                  float* __restrict__ OUT) {
    constexpr int CQ = F / 4;
    constexpr int NPB = 256 / CQ;
    int node = blockIdx.x * NPB + threadIdx.x / CQ;
    int q = (threadIdx.x % CQ) * 4;
    if (node >= NN) return;
    float dn = dinv[node];
    float4 acc = *(const float4*)&Hs[(size_t)node * F + q];  // self loop term
    int e = rs[node];
    int e1 = rs[node + 1];
    for (; e + 4 <= e1; e += 4) {
        int s0 = csr[e], s1 = csr[e + 1], s2 = csr[e + 2], s3 = csr[e + 3];
        float4 h0 = *(const float4*)&Hs[(size_t)s0 * F + q];
        float4 h1 = *(const float4*)&Hs[(size_t)s1 * F + q];
        float4 h2 = *(const float4*)&Hs[(size_t)s2 * F + q];
        float4 h3 = *(const float4*)&Hs[(size_t)s3 * F + q];
        acc = f4_add(acc, f4_add(f4_add(h0, h1), f4_add(h2, h3)));
    }
    for (; e < e1; e++) {
        int s = csr[e];
        acc = f4_add(acc, *(const float4*)&Hs[(size_t)s * F + q]);
    }
    float4 bv = *(const float4*)&bias[q];
    float4 o = f4_fma(dn, acc, bv);
    if (RELU) {
        o.x = fmaxf(o.x, 0.f); o.y = fmaxf(o.y, 0.f);
        o.z = fmaxf(o.z, 0.f); o.w = fmaxf(o.w, 0.f);
    }
    *(float4*)&OUT[(size_t)node * F + q] = o;
}

extern "C" void kernel_launch(void* const* d_in, const int* in_sizes, int n_in,
                              void* d_out, int out_size, void* d_ws, size_t ws_size,
                              hipStream_t stream) {
    const float* x  = (const float*)d_in[0];
    const void* eidx = d_in[1];
    const float* W1 = (const float*)d_in[2];
    const float* b1 = (const float*)d_in[3];
    const float* W2 = (const float*)d_in[4];
    const float* b2 = (const float*)d_in[5];
    const float* W3 = (const float*)d_in[6];
    const float* b3 = (const float*)d_in[7];
    float* out = (float*)d_out;

    char* ws = (char*)d_ws;
    size_t off = 0;
    auto alloc = [&](size_t bytes) -> void* {
        void* p = ws + off;
        off += (bytes + 255) & ~(size_t)255;
        return p;
    };
    // bufB (51.2 MB) overlaps CSR-build scratch (dead before agg1 writes bufB)
    float* bufB = (float*)alloc((size_t)NN * 128 * 4);
    int* buckets  = (int*)bufB;                                          // NB*BCAP ints (12.8 MB)
    int* bcnt     = (int*)((char*)bufB + (size_t)NB * BCAP * 4);         // NB ints
    int* deg      = (int*)((char*)bufB + (size_t)NB * BCAP * 4 + 4096);  // NN ints
    int* blocksum = (int*)((char*)deg + (size_t)NN * 4);                 // SCAN_BLOCKS ints
    int* row_start = (int*)alloc((size_t)(NN + 1) * 4);
    float* dinv = (float*)alloc((size_t)NN * 4);
    int* flagp  = (int*)alloc(256);
    int* csr    = (int*)alloc((size_t)NE * 4);
    float* bufA = (float*)alloc((size_t)NN * 128 * 4);

    hipMemsetAsync(bcnt, 0, (size_t)NB * 4, stream);
    detect_flag_kernel<<<1, 256, 0, stream>>>((const int*)eidx, flagp);
    bucket_kernel<<<NE / 256, 256, 0, stream>>>(eidx, flagp, bcnt, buckets);
    hist_kernel<<<NB, 256, 0, stream>>>(bcnt, buckets, deg);
    dinv_kernel<<<(NN + 255) / 256, 256, 0, stream>>>(deg, dinv);
    scanA_kernel<<<SCAN_BLOCKS, 256, 0, stream>>>(deg, blocksum);
    scanC_kernel<<<SCAN_BLOCKS, 256, 0, stream>>>(deg, blocksum, row_start);
    csrfill_kernel<<<NB, 256, 0, stream>>>(bcnt, buckets, row_start, csr);

    // Layer 1
    gemm_kernel<128><<<NN / 32, 256, 0, stream>>>(x, W1, dinv, bufA, NN);
    agg_kernel<128, true><<<NN / 8, 256, 0, stream>>>(bufA, row_start, csr, dinv, b1, bufB);
    // Layer 2
    gemm_kernel<128><<<NN / 32, 256, 0, stream>>>(bufB, W2, dinv, bufA, NN);
    agg_kernel<128, true><<<NN / 8, 256, 0, stream>>>(bufA, row_start, csr, dinv, b2, bufB);
    // Layer 3 (128 -> 64, no relu)
    gemm_kernel<64><<<(NN + 63) / 64, 256, 0, stream>>>(bufB, W3, dinv, bufA, NN);
    agg_kernel<64, false><<<NN / 16, 256, 0, stream>>>(bufA, row_start, csr, dinv, b3, out);
}

// Round 4
// 801.539 us; speedup vs baseline: 1.2506x; 1.2506x over previous
//
#include <hip/hip_runtime.h>
#include <cstdint>
#include <cstddef>

#define NN 100000
#define NE 1600000
#define SCAN_BLOCKS ((NN + 1023) / 1024)   // 98

__device__ __forceinline__ float4 f4_fma(float s, float4 a, float4 acc) {
    acc.x += s * a.x; acc.y += s * a.y; acc.z += s * a.z; acc.w += s * a.w;
    return acc;
}
__device__ __forceinline__ float4 f4_add(float4 a, float4 b) {
    return make_float4(a.x + b.x, a.y + b.y, a.z + b.z, a.w + b.w);
}

// Detect edge_index storage: int64 (odd 32-bit words all zero, values < 2^31)
// vs int32 (odd words are random node ids).
__global__ void detect_flag_kernel(const int* __restrict__ idx, int* __restrict__ flag) {
    __shared__ int cnt;
    if (threadIdx.x == 0) cnt = 0;
    __syncthreads();
    if (idx[2 * threadIdx.x + 1] == 0) atomicAdd(&cnt, 1);
    __syncthreads();
    if (threadIdx.x == 0) *flag = (cnt == (int)blockDim.x) ? 1 : 0;
}

// Degree pass: read dst half of edge_index directly. 100K counters, ~16
// claims each -> low per-line atomic fan-in (the R3 lesson).
__global__ void deg_kernel(const void* __restrict__ idx, const int* __restrict__ flag,
                           int* __restrict__ deg) {
    int e = blockIdx.x * blockDim.x + threadIdx.x;
    if (e >= NE) return;
    int d_ = (*flag) ? (int)((const long long*)idx)[NE + e]
                     : ((const int*)idx)[NE + e];
    atomicAdd(&deg[d_], 1);
}

__global__ void dinv_kernel(const int* __restrict__ deg, float* __restrict__ dinv) {
    int n = blockIdx.x * blockDim.x + threadIdx.x;
    if (n < NN) dinv[n] = rsqrtf((float)(deg[n] + 1));  // +1 self loop
}

// Hierarchical scan, pass 1: per-1024-chunk sums.
__global__ __launch_bounds__(256) void scanA_kernel(const int* __restrict__ deg,
                                                    int* __restrict__ blocksum) {
    __shared__ int red[256];
    int t = threadIdx.x;
    int base = blockIdx.x * 1024 + t * 4;
    int s = 0;
#pragma unroll
    for (int j = 0; j < 4; j++) { int i = base + j; if (i < NN) s += deg[i]; }
    red[t] = s;
    __syncthreads();
    for (int off = 128; off > 0; off >>= 1) {
        if (t < off) red[t] += red[t + off];
        __syncthreads();
    }
    if (t == 0) blocksum[blockIdx.x] = red[0];
}

// Scan pass 2: per-chunk exclusive scan + chunk offset -> row_start + cursor.
__global__ __launch_bounds__(256) void scanC_kernel(const int* __restrict__ deg,
                                                    const int* __restrict__ blocksum,
                                                    int* __restrict__ row_start,
                                                    int* __restrict__ cursor) {
    __shared__ int lds[256];
    __shared__ int boff_s;
    int t = threadIdx.x;
    int b = blockIdx.x;
    lds[t] = (t < b && t < SCAN_BLOCKS) ? blocksum[t] : 0;
    __syncthreads();
    for (int off = 128; off > 0; off >>= 1) {
        if (t < off) lds[t] += lds[t + off];
        __syncthreads();
    }
    if (t == 0) boff_s = lds[0];
    __syncthreads();
    int boff = boff_s;

    int base = b * 1024 + t * 4;
    int d[4]; int s = 0;
#pragma unroll
    for (int j = 0; j < 4; j++) { int i = base + j; d[j] = (i < NN) ? deg[i] : 0; s += d[j]; }
    __syncthreads();
    lds[t] = s;
    __syncthreads();
    for (int off = 1; off < 256; off <<= 1) {
        int u = (t >= off) ? lds[t - off] : 0;
        __syncthreads();
        lds[t] += u;
        __syncthreads();
    }
    int offr = boff + ((t == 0) ? 0 : lds[t - 1]);
#pragma unroll
    for (int j = 0; j < 4; j++) {
        int i = base + j;
        if (i < NN) { row_start[i] = offr; cursor[i] = offr; offr += d[j]; }
    }
    if (b == 0 && t == 0) row_start[NN] = NE;
}

// CSR fill, direct from edge_index (no src/dst intermediates).
__global__ void fill_kernel(const void* __restrict__ idx, const int* __restrict__ flag,
                            int* __restrict__ cursor, int* __restrict__ csr) {
    int e = blockIdx.x * blockDim.x + threadIdx.x;
    if (e >= NE) return;
    int s_, d_;
    if (*flag) {
        const long long* p = (const long long*)idx;
        s_ = (int)p[e]; d_ = (int)p[NE + e];
    } else {
        const int* p = (const int*)idx;
        s_ = p[e]; d_ = p[NE + e];
    }
    int pos = atomicAdd(&cursor[d_], 1);
    csr[pos] = s_;
}

// H[N,F] = dinv[r] * (X[N,128] @ W[128,F]).  fp32 vector GEMM, W in LDS.
template <int F>
__global__ __launch_bounds__(256) void gemm_kernel(const float* __restrict__ X,
                                                   const float* __restrict__ W,
                                                   const float* __restrict__ dinv,
                                                   float* __restrict__ H, int N) {
    constexpr int K = 128;
    constexpr int CQ = F / 4;
    constexpr int RS = 256 / CQ;
    constexpr int ROWS = RS * 4;
    __shared__ float Wlds[K * F];
    for (int i = threadIdx.x; i < K * F / 4; i += 256)
        ((float4*)Wlds)[i] = ((const float4*)W)[i];
    __syncthreads();

    int c = (threadIdx.x % CQ) * 4;
    int r0 = blockIdx.x * ROWS + (threadIdx.x / CQ) * 4;
    float4 acc[4];
#pragma unroll
    for (int i = 0; i < 4; i++) acc[i] = make_float4(0.f, 0.f, 0.f, 0.f);

    for (int k = 0; k < K; k += 4) {
        float4 xv[4];
#pragma unroll
        for (int i = 0; i < 4; i++) {
            int rr = r0 + i; if (rr >= N) rr = N - 1;
            xv[i] = *(const float4*)&X[(size_t)rr * K + k];
        }
#pragma unroll
        for (int j = 0; j < 4; j++) {
            float4 wv = *(const float4*)&Wlds[(k + j) * F + c];
#pragma unroll
            for (int i = 0; i < 4; i++) {
                float xk = ((const float*)&xv[i])[j];
                acc[i] = f4_fma(xk, wv, acc[i]);
            }
        }
    }
#pragma unroll
    for (int i = 0; i < 4; i++) {
        int rr = r0 + i;
        if (rr < N) {
            float dv = dinv[rr];
            float4 o = make_float4(dv * acc[i].x, dv * acc[i].y, dv * acc[i].z, dv * acc[i].w);
            *(float4*)&H[(size_t)rr * F + c] = o;
        }
    }
}

// Hs is pre-scaled by dinv[row].  OUT[n] = (relu?)( b + dn * (Hs[n] + sum_e Hs[src]) )
template <int F, bool RELU>
__global__ __launch_bounds__(256) void agg_kernel(const float* __restrict__ Hs,
                                                  const int* __restrict__ rs,
                                                  const int* __restrict__ csr,
                                                  const float* __restrict__ dinv,
                                                  const float* __restrict__ bias,
                                                  float* __restrict__ OUT) {
    constexpr int CQ = F / 4;
    constexpr int NPB = 256 / CQ;
    int node = blockIdx.x * NPB + threadIdx.x / CQ;
    int q = (threadIdx.x % CQ) * 4;
    if (node >= NN) return;
    float dn = dinv[node];
    float4 acc = *(const float4*)&Hs[(size_t)node * F + q];  // self loop term
    int e = rs[node];
    int e1 = rs[node + 1];
    // unroll x8: 8 independent 512B row-gathers in flight per thread
    for (; e + 8 <= e1; e += 8) {
        int s[8];
#pragma unroll
        for (int j = 0; j < 8; j++) s[j] = csr[e + j];
        float4 h[8];
#pragma unroll
        for (int j = 0; j < 8; j++) h[j] = *(const float4*)&Hs[(size_t)s[j] * F + q];
        float4 a0 = f4_add(f4_add(h[0], h[1]), f4_add(h[2], h[3]));
        float4 a1 = f4_add(f4_add(h[4], h[5]), f4_add(h[6], h[7]));
        acc = f4_add(acc, f4_add(a0, a1));
    }
    for (; e + 4 <= e1; e += 4) {
        int s0 = csr[e], s1 = csr[e + 1], s2 = csr[e + 2], s3 = csr[e + 3];
        float4 h0 = *(const float4*)&Hs[(size_t)s0 * F + q];
        float4 h1 = *(const float4*)&Hs[(size_t)s1 * F + q];
        float4 h2 = *(const float4*)&Hs[(size_t)s2 * F + q];
        float4 h3 = *(const float4*)&Hs[(size_t)s3 * F + q];
        acc = f4_add(acc, f4_add(f4_add(h0, h1), f4_add(h2, h3)));
    }
    for (; e < e1; e++) {
        int s = csr[e];
        acc = f4_add(acc, *(const float4*)&Hs[(size_t)s * F + q]);
    }
    float4 bv = *(const float4*)&bias[q];
    float4 o = f4_fma(dn, acc, bv);
    if (RELU) {
        o.x = fmaxf(o.x, 0.f); o.y = fmaxf(o.y, 0.f);
        o.z = fmaxf(o.z, 0.f); o.w = fmaxf(o.w, 0.f);
    }
    *(float4*)&OUT[(size_t)node * F + q] = o;
}

extern "C" void kernel_launch(void* const* d_in, const int* in_sizes, int n_in,
                              void* d_out, int out_size, void* d_ws, size_t ws_size,
                              hipStream_t stream) {
    const float* x  = (const float*)d_in[0];
    const void* eidx = d_in[1];
    const float* W1 = (const float*)d_in[2];
    const float* b1 = (const float*)d_in[3];
    const float* W2 = (const float*)d_in[4];
    const float* b2 = (const float*)d_in[5];
    const float* W3 = (const float*)d_in[6];
    const float* b3 = (const float*)d_in[7];
    float* out = (float*)d_out;

    char* ws = (char*)d_ws;
    size_t off = 0;
    auto alloc = [&](size_t bytes) -> void* {
        void* p = ws + off;
        off += (bytes + 255) & ~(size_t)255;
        return p;
    };
    // bufB (51.2 MB) overlaps CSR-build scratch (deg/blocksum dead before agg1)
    float* bufB = (float*)alloc((size_t)NN * 128 * 4);
    int* deg      = (int*)bufB;                                  // NN ints
    int* blocksum = (int*)((char*)bufB + (size_t)NN * 4);        // SCAN_BLOCKS ints
    int* row_start = (int*)alloc((size_t)(NN + 1) * 4);
    int* cursor    = (int*)alloc((size_t)NN * 4);
    float* dinv = (float*)alloc((size_t)NN * 4);
    int* flagp  = (int*)alloc(256);
    int* csr    = (int*)alloc((size_t)NE * 4);
    float* bufA = (float*)alloc((size_t)NN * 128 * 4);

    hipMemsetAsync(deg, 0, (size_t)NN * 4, stream);
    detect_flag_kernel<<<1, 256, 0, stream>>>((const int*)eidx, flagp);
    deg_kernel<<<NE / 256, 256, 0, stream>>>(eidx, flagp, deg);
    dinv_kernel<<<(NN + 255) / 256, 256, 0, stream>>>(deg, dinv);
    scanA_kernel<<<SCAN_BLOCKS, 256, 0, stream>>>(deg, blocksum);
    scanC_kernel<<<SCAN_BLOCKS, 256, 0, stream>>>(deg, blocksum, row_start, cursor);
    fill_kernel<<<NE / 256, 256, 0, stream>>>(eidx, flagp, cursor, csr);

    // Layer 1
    gemm_kernel<128><<<NN / 32, 256, 0, stream>>>(x, W1, dinv, bufA, NN);
    agg_kernel<128, true><<<NN / 8, 256, 0, stream>>>(bufA, row_start, csr, dinv, b1, bufB);
    // Layer 2
    gemm_kernel<128><<<NN / 32, 256, 0, stream>>>(bufB, W2, dinv, bufA, NN);
    agg_kernel<128, true><<<NN / 8, 256, 0, stream>>>(bufA, row_start, csr, dinv, b2, bufB);
    // Layer 3 (128 -> 64, no relu)
    gemm_kernel<64><<<(NN + 63) / 64, 256, 0, stream>>>(bufB, W3, dinv, bufA, NN);
    agg_kernel<64, false><<<NN / 16, 256, 0, stream>>>(bufA, row_start, csr, dinv, b3, out);
}

// Round 5
// 662.156 us; speedup vs baseline: 1.5139x; 1.2105x over previous
//
#include <hip/hip_runtime.h>
#include <cstdint>
#include <cstddef>

#define NN 100000
#define NE 1600000
#define SCAN_BLOCKS ((NN + 1023) / 1024)   // 98
#define NBK ((NN + 255) / 256)             // 391 dst-buckets of 256 nodes
#define BCAP 4608                          // mean 4092, std ~64 -> 8 sigma slack
#define EPB 4096                           // edges per bin block
#define BIN_BLOCKS ((NE + EPB - 1) / EPB)  // 391

__device__ __forceinline__ float4 f4_fma(float s, float4 a, float4 acc) {
    acc.x += s * a.x; acc.y += s * a.y; acc.z += s * a.z; acc.w += s * a.w;
    return acc;
}
__device__ __forceinline__ float4 f4_add(float4 a, float4 b) {
    return make_float4(a.x + b.x, a.y + b.y, a.z + b.z, a.w + b.w);
}

// Detect edge_index storage: int64 (odd 32-bit words all zero, values < 2^31)
// vs int32 (odd words are random node ids).
__global__ void detect_flag_kernel(const int* __restrict__ idx, int* __restrict__ flag) {
    __shared__ int cnt;
    if (threadIdx.x == 0) cnt = 0;
    __syncthreads();
    if (idx[2 * threadIdx.x + 1] == 0) atomicAdd(&cnt, 1);
    __syncthreads();
    if (threadIdx.x == 0) *flag = (cnt == (int)blockDim.x) ? 1 : 0;
}

// Phase 1: per-block LDS binning + one padded global atomic per (block,bucket)
// bulk reservation; scatter packed (src<<8 | dst&255) into bucket regions.
// Each block's global writes span ~16KB issued within ~us on one XCD -> L2
// coalesces the 4B stores into dense line writebacks (the R4 lesson: density
// in TIME+XCD, not just address space).
__global__ __launch_bounds__(256) void bin_kernel(const void* __restrict__ idx,
                                                  const int* __restrict__ flag,
                                                  int* __restrict__ gcnt,       // NBK, stride 16
                                                  int* __restrict__ bucketbuf) {
    __shared__ int cnt[NBK];
    __shared__ int gbase[NBK];
    int t = threadIdx.x;
    long long base = (long long)blockIdx.x * EPB;
    for (int i = t; i < NBK; i += 256) cnt[i] = 0;
    __syncthreads();
    bool is64 = (*flag != 0);
    int lpos[16];
#pragma unroll
    for (int j = 0; j < 16; j++) {
        long long e = base + j * 256 + t;
        lpos[j] = 0;
        if (e < NE) {
            int d_ = is64 ? (int)((const long long*)idx)[NE + e]
                          : ((const int*)idx)[NE + e];
            lpos[j] = atomicAdd(&cnt[d_ >> 8], 1);
        }
    }
    __syncthreads();
    for (int b = t; b < NBK; b += 256) {
        int c = cnt[b];
        gbase[b] = (c > 0) ? atomicAdd(&gcnt[b * 16], c) : 0;
    }
    __syncthreads();
#pragma unroll
    for (int j = 0; j < 16; j++) {
        long long e = base + j * 256 + t;
        if (e < NE) {
            int s_, d_;
            if (is64) { const long long* p = (const long long*)idx; s_ = (int)p[e]; d_ = (int)p[NE + e]; }
            else      { const int* p = (const int*)idx;             s_ = p[e];      d_ = p[NE + e]; }
            int b = d_ >> 8;
            int pos = gbase[b] + lpos[j];
            if (pos < BCAP) bucketbuf[(size_t)b * BCAP + pos] = (s_ << 8) | (d_ & 255);
        }
    }
}

// Phase 2a: per-bucket LDS histogram -> deg (dense write, no global atomics).
__global__ __launch_bounds__(256) void hist_kernel(const int* __restrict__ gcnt,
                                                   const int* __restrict__ bucketbuf,
                                                   int* __restrict__ deg) {
    __shared__ int cnt[256];
    int t = threadIdx.x, b = blockIdx.x;
    cnt[t] = 0;
    __syncthreads();
    int n = gcnt[b * 16]; if (n > BCAP) n = BCAP;
    for (int i = t; i < n; i += 256)
        atomicAdd(&cnt[bucketbuf[(size_t)b * BCAP + i] & 255], 1);
    __syncthreads();
    int node = b * 256 + t;
    if (node < NN) deg[node] = cnt[t];
}

__global__ void dinv_kernel(const int* __restrict__ deg, float* __restrict__ dinv) {
    int n = blockIdx.x * blockDim.x + threadIdx.x;
    if (n < NN) dinv[n] = rsqrtf((float)(deg[n] + 1));  // +1 self loop
}

// Hierarchical scan, pass 1: per-1024-chunk sums.
__global__ __launch_bounds__(256) void scanA_kernel(const int* __restrict__ deg,
                                                    int* __restrict__ blocksum) {
    __shared__ int red[256];
    int t = threadIdx.x;
    int base = blockIdx.x * 1024 + t * 4;
    int s = 0;
#pragma unroll
    for (int j = 0; j < 4; j++) { int i = base + j; if (i < NN) s += deg[i]; }
    red[t] = s;
    __syncthreads();
    for (int off = 128; off > 0; off >>= 1) {
        if (t < off) red[t] += red[t + off];
        __syncthreads();
    }
    if (t == 0) blocksum[blockIdx.x] = red[0];
}

// Scan pass 2: per-chunk exclusive scan + chunk offset -> row_start.
__global__ __launch_bounds__(256) void scanC_kernel(const int* __restrict__ deg,
                                                    const int* __restrict__ blocksum,
                                                    int* __restrict__ row_start) {
    __shared__ int lds[256];
    __shared__ int boff_s;
    int t = threadIdx.x;
    int b = blockIdx.x;
    lds[t] = (t < b && t < SCAN_BLOCKS) ? blocksum[t] : 0;
    __syncthreads();
    for (int off = 128; off > 0; off >>= 1) {
        if (t < off) lds[t] += lds[t + off];
        __syncthreads();
    }
    if (t == 0) boff_s = lds[0];
    __syncthreads();
    int boff = boff_s;

    int base = b * 1024 + t * 4;
    int d[4]; int s = 0;
#pragma unroll
    for (int j = 0; j < 4; j++) { int i = base + j; d[j] = (i < NN) ? deg[i] : 0; s += d[j]; }
    __syncthreads();
    lds[t] = s;
    __syncthreads();
    for (int off = 1; off < 256; off <<= 1) {
        int u = (t >= off) ? lds[t - off] : 0;
        __syncthreads();
        lds[t] += u;
        __syncthreads();
    }
    int offr = boff + ((t == 0) ? 0 : lds[t - 1]);
#pragma unroll
    for (int j = 0; j < 4; j++) {
        int i = base + j;
        if (i < NN) { row_start[i] = offr; offr += d[j]; }
    }
    if (b == 0 && t == 0) row_start[NN] = NE;
}

// Phase 2b: per-bucket scatter into CSR via LDS cursors; writes confined to
// the bucket's ~16KB csr window from one block -> dense L2 writeback.
__global__ __launch_bounds__(256) void csrfill_kernel(const int* __restrict__ gcnt,
                                                      const int* __restrict__ bucketbuf,
                                                      const int* __restrict__ row_start,
                                                      int* __restrict__ csr) {
    __shared__ int cur[256];
    int t = threadIdx.x, b = blockIdx.x;
    int node = b * 256 + t;
    cur[t] = (node < NN) ? row_start[node] : 0;
    __syncthreads();
    int n = gcnt[b * 16]; if (n > BCAP) n = BCAP;
    for (int i = t; i < n; i += 256) {
        int v = bucketbuf[(size_t)b * BCAP + i];
        int pos = atomicAdd(&cur[v & 255], 1);
        csr[pos] = v >> 8;
    }
}

// H[N,F] = dinv[r] * (X[N,128] @ W[128,F]).  fp32 vector GEMM, W in LDS.
template <int F>
__global__ __launch_bounds__(256) void gemm_kernel(const float* __restrict__ X,
                                                   const float* __restrict__ W,
                                                   const float* __restrict__ dinv,
                                                   float* __restrict__ H, int N) {
    constexpr int K = 128;
    constexpr int CQ = F / 4;
    constexpr int RS = 256 / CQ;
    constexpr int ROWS = RS * 4;
    __shared__ float Wlds[K * F];
    for (int i = threadIdx.x; i < K * F / 4; i += 256)
        ((float4*)Wlds)[i] = ((const float4*)W)[i];
    __syncthreads();

    int c = (threadIdx.x % CQ) * 4;
    int r0 = blockIdx.x * ROWS + (threadIdx.x / CQ) * 4;
    float4 acc[4];
#pragma unroll
    for (int i = 0; i < 4; i++) acc[i] = make_float4(0.f, 0.f, 0.f, 0.f);

    for (int k = 0; k < K; k += 4) {
        float4 xv[4];
#pragma unroll
        for (int i = 0; i < 4; i++) {
            int rr = r0 + i; if (rr >= N) rr = N - 1;
            xv[i] = *(const float4*)&X[(size_t)rr * K + k];
        }
#pragma unroll
        for (int j = 0; j < 4; j++) {
            float4 wv = *(const float4*)&Wlds[(k + j) * F + c];
#pragma unroll
            for (int i = 0; i < 4; i++) {
                float xk = ((const float*)&xv[i])[j];
                acc[i] = f4_fma(xk, wv, acc[i]);
            }
        }
    }
#pragma unroll
    for (int i = 0; i < 4; i++) {
        int rr = r0 + i;
        if (rr < N) {
            float dv = dinv[rr];
            float4 o = make_float4(dv * acc[i].x, dv * acc[i].y, dv * acc[i].z, dv * acc[i].w);
            *(float4*)&H[(size_t)rr * F + c] = o;
        }
    }
}

// Hs is pre-scaled by dinv[row].  OUT[n] = (relu?)( b + dn * (Hs[n] + sum_e Hs[src]) )
template <int F, bool RELU>
__global__ __launch_bounds__(256) void agg_kernel(const float* __restrict__ Hs,
                                                  const int* __restrict__ rs,
                                                  const int* __restrict__ csr,
                                                  const float* __restrict__ dinv,
                                                  const float* __restrict__ bias,
                                                  float* __restrict__ OUT) {
    constexpr int CQ = F / 4;
    constexpr int NPB = 256 / CQ;
    int node = blockIdx.x * NPB + threadIdx.x / CQ;
    int q = (threadIdx.x % CQ) * 4;
    if (node >= NN) return;
    float dn = dinv[node];
    float4 acc = *(const float4*)&Hs[(size_t)node * F + q];  // self loop term
    int e = rs[node];
    int e1 = rs[node + 1];
    for (; e + 8 <= e1; e += 8) {
        int s[8];
#pragma unroll
        for (int j = 0; j < 8; j++) s[j] = csr[e + j];
        float4 h[8];
#pragma unroll
        for (int j = 0; j < 8; j++) h[j] = *(const float4*)&Hs[(size_t)s[j] * F + q];
        float4 a0 = f4_add(f4_add(h[0], h[1]), f4_add(h[2], h[3]));
        float4 a1 = f4_add(f4_add(h[4], h[5]), f4_add(h[6], h[7]));
        acc = f4_add(acc, f4_add(a0, a1));
    }
    for (; e + 4 <= e1; e += 4) {
        int s0 = csr[e], s1 = csr[e + 1], s2 = csr[e + 2], s3 = csr[e + 3];
        float4 h0 = *(const float4*)&Hs[(size_t)s0 * F + q];
        float4 h1 = *(const float4*)&Hs[(size_t)s1 * F + q];
        float4 h2 = *(const float4*)&Hs[(size_t)s2 * F + q];
        float4 h3 = *(const float4*)&Hs[(size_t)s3 * F + q];
        acc = f4_add(acc, f4_add(f4_add(h0, h1), f4_add(h2, h3)));
    }
    for (; e < e1; e++) {
        int s = csr[e];
        acc = f4_add(acc, *(const float4*)&Hs[(size_t)s * F + q]);
    }
    float4 bv = *(const float4*)&bias[q];
    float4 o = f4_fma(dn, acc, bv);
    if (RELU) {
        o.x = fmaxf(o.x, 0.f); o.y = fmaxf(o.y, 0.f);
        o.z = fmaxf(o.z, 0.f); o.w = fmaxf(o.w, 0.f);
    }
    *(float4*)&OUT[(size_t)node * F + q] = o;
}

extern "C" void kernel_launch(void* const* d_in, const int* in_sizes, int n_in,
                              void* d_out, int out_size, void* d_ws, size_t ws_size,
                              hipStream_t stream) {
    const float* x  = (const float*)d_in[0];
    const void* eidx = d_in[1];
    const float* W1 = (const float*)d_in[2];
    const float* b1 = (const float*)d_in[3];
    const float* W2 = (const float*)d_in[4];
    const float* b2 = (const float*)d_in[5];
    const float* W3 = (const float*)d_in[6];
    const float* b3 = (const float*)d_in[7];
    float* out = (float*)d_out;

    char* ws = (char*)d_ws;
    size_t off = 0;
    auto alloc = [&](size_t bytes) -> void* {
        void* p = ws + off;
        off += (bytes + 255) & ~(size_t)255;
        return p;
    };
    // bufB overlaps deg/blocksum (dead before agg1 writes bufB);
    // bufA overlaps bucketbuf/gcnt (dead before gemm1 writes bufA).
    float* bufB = (float*)alloc((size_t)NN * 128 * 4);
    int* deg      = (int*)bufB;                                  // NN ints
    int* blocksum = (int*)((char*)bufB + (size_t)NN * 4);        // SCAN_BLOCKS ints
    int* row_start = (int*)alloc((size_t)(NN + 1) * 4);
    float* dinv = (float*)alloc((size_t)NN * 4);
    int* flagp  = (int*)alloc(256);
    int* csr    = (int*)alloc((size_t)NE * 4);
    float* bufA = (float*)alloc((size_t)NN * 128 * 4);
    int* bucketbuf = (int*)bufA;                                    // NBK*BCAP ints (7.2MB)
    int* gcnt      = (int*)((char*)bufA + (size_t)NBK * BCAP * 4);  // NBK*16 ints, line-padded

    hipMemsetAsync(gcnt, 0, (size_t)NBK * 16 * 4, stream);
    detect_flag_kernel<<<1, 256, 0, stream>>>((const int*)eidx, flagp);
    bin_kernel<<<BIN_BLOCKS, 256, 0, stream>>>(eidx, flagp, gcnt, bucketbuf);
    hist_kernel<<<NBK, 256, 0, stream>>>(gcnt, bucketbuf, deg);
    dinv_kernel<<<(NN + 255) / 256, 256, 0, stream>>>(deg, dinv);
    scanA_kernel<<<SCAN_BLOCKS, 256, 0, stream>>>(deg, blocksum);
    scanC_kernel<<<SCAN_BLOCKS, 256, 0, stream>>>(deg, blocksum, row_start);
    csrfill_kernel<<<NBK, 256, 0, stream>>>(gcnt, bucketbuf, row_start, csr);

    // Layer 1
    gemm_kernel<128><<<NN / 32, 256, 0, stream>>>(x, W1, dinv, bufA, NN);
    agg_kernel<128, true><<<NN / 8, 256, 0, stream>>>(bufA, row_start, csr, dinv, b1, bufB);
    // Layer 2
    gemm_kernel<128><<<NN / 32, 256, 0, stream>>>(bufB, W2, dinv, bufA, NN);
    agg_kernel<128, true><<<NN / 8, 256, 0, stream>>>(bufA, row_start, csr, dinv, b2, bufB);
    // Layer 3 (128 -> 64, no relu)
    gemm_kernel<64><<<(NN + 63) / 64, 256, 0, stream>>>(bufB, W3, dinv, bufA, NN);
    agg_kernel<64, false><<<NN / 16, 256, 0, stream>>>(bufA, row_start, csr, dinv, b3, out);
}

// Round 6
// 529.473 us; speedup vs baseline: 1.8933x; 1.2506x over previous
//
#include <hip/hip_runtime.h>
#include <hip/hip_fp16.h>
#include <cstdint>
#include <cstddef>

#define NN 100000
#define NE 1600000
#define SCAN_BLOCKS ((NN + 1023) / 1024)   // 98
#define NBK ((NN + 255) / 256)             // 391 dst-buckets of 256 nodes
#define BCAP 4608                          // mean 4092, std ~64 -> 8 sigma slack
#define EPB 4096                           // edges per bin block
#define BIN_BLOCKS ((NE + EPB - 1) / EPB)  // 391

__device__ __forceinline__ float4 f4_fma(float s, float4 a, float4 acc) {
    acc.x += s * a.x; acc.y += s * a.y; acc.z += s * a.z; acc.w += s * a.w;
    return acc;
}

union F4H8 { float4 f4; __half2 h2[4]; };  // 16 B = 8 halves

__device__ __forceinline__ uint2 pack4half(float4 v) {
    __half2 a = __floats2half2_rn(v.x, v.y);
    __half2 b = __floats2half2_rn(v.z, v.w);
    uint2 r;
    r.x = *(unsigned int*)&a;
    r.y = *(unsigned int*)&b;
    return r;
}

// Detect edge_index storage: int64 (odd 32-bit words all zero, values < 2^31)
// vs int32 (odd words are random node ids).
__global__ void detect_flag_kernel(const int* __restrict__ idx, int* __restrict__ flag) {
    __shared__ int cnt;
    if (threadIdx.x == 0) cnt = 0;
    __syncthreads();
    if (idx[2 * threadIdx.x + 1] == 0) atomicAdd(&cnt, 1);
    __syncthreads();
    if (threadIdx.x == 0) *flag = (cnt == (int)blockDim.x) ? 1 : 0;
}

// Phase 1: per-block LDS binning + one padded global atomic per (block,bucket)
// bulk reservation; scatter packed (src<<8 | dst&255) into bucket regions.
__global__ __launch_bounds__(256) void bin_kernel(const void* __restrict__ idx,
                                                  const int* __restrict__ flag,
                                                  int* __restrict__ gcnt,       // NBK, stride 16
                                                  int* __restrict__ bucketbuf) {
    __shared__ int cnt[NBK];
    __shared__ int gbase[NBK];
    int t = threadIdx.x;
    long long base = (long long)blockIdx.x * EPB;
    for (int i = t; i < NBK; i += 256) cnt[i] = 0;
    __syncthreads();
    bool is64 = (*flag != 0);
    int lpos[16];
#pragma unroll
    for (int j = 0; j < 16; j++) {
        long long e = base + j * 256 + t;
        lpos[j] = 0;
        if (e < NE) {
            int d_ = is64 ? (int)((const long long*)idx)[NE + e]
                          : ((const int*)idx)[NE + e];
            lpos[j] = atomicAdd(&cnt[d_ >> 8], 1);
        }
    }
    __syncthreads();
    for (int b = t; b < NBK; b += 256) {
        int c = cnt[b];
        gbase[b] = (c > 0) ? atomicAdd(&gcnt[b * 16], c) : 0;
    }
    __syncthreads();
#pragma unroll
    for (int j = 0; j < 16; j++) {
        long long e = base + j * 256 + t;
        if (e < NE) {
            int s_, d_;
            if (is64) { const long long* p = (const long long*)idx; s_ = (int)p[e]; d_ = (int)p[NE + e]; }
            else      { const int* p = (const int*)idx;             s_ = p[e];      d_ = p[NE + e]; }
            int b = d_ >> 8;
            int pos = gbase[b] + lpos[j];
            if (pos < BCAP) bucketbuf[(size_t)b * BCAP + pos] = (s_ << 8) | (d_ & 255);
        }
    }
}

// Phase 2a: per-bucket LDS histogram -> deg (dense write, no global atomics).
__global__ __launch_bounds__(256) void hist_kernel(const int* __restrict__ gcnt,
                                                   const int* __restrict__ bucketbuf,
                                                   int* __restrict__ deg) {
    __shared__ int cnt[256];
    int t = threadIdx.x, b = blockIdx.x;
    cnt[t] = 0;
    __syncthreads();
    int n = gcnt[b * 16]; if (n > BCAP) n = BCAP;
    for (int i = t; i < n; i += 256)
        atomicAdd(&cnt[bucketbuf[(size_t)b * BCAP + i] & 255], 1);
    __syncthreads();
    int node = b * 256 + t;
    if (node < NN) deg[node] = cnt[t];
}

__global__ void dinv_kernel(const int* __restrict__ deg, float* __restrict__ dinv) {
    int n = blockIdx.x * blockDim.x + threadIdx.x;
    if (n < NN) dinv[n] = rsqrtf((float)(deg[n] + 1));  // +1 self loop
}

// Hierarchical scan, pass 1: per-1024-chunk sums.
__global__ __launch_bounds__(256) void scanA_kernel(const int* __restrict__ deg,
                                                    int* __restrict__ blocksum) {
    __shared__ int red[256];
    int t = threadIdx.x;
    int base = blockIdx.x * 1024 + t * 4;
    int s = 0;
#pragma unroll
    for (int j = 0; j < 4; j++) { int i = base + j; if (i < NN) s += deg[i]; }
    red[t] = s;
    __syncthreads();
    for (int off = 128; off > 0; off >>= 1) {
        if (t < off) red[t] += red[t + off];
        __syncthreads();
    }
    if (t == 0) blocksum[blockIdx.x] = red[0];
}

// Scan pass 2: per-chunk exclusive scan + chunk offset -> row_start.
__global__ __launch_bounds__(256) void scanC_kernel(const int* __restrict__ deg,
                                                    const int* __restrict__ blocksum,
                                                    int* __restrict__ row_start) {
    __shared__ int lds[256];
    __shared__ int boff_s;
    int t = threadIdx.x;
    int b = blockIdx.x;
    lds[t] = (t < b && t < SCAN_BLOCKS) ? blocksum[t] : 0;
    __syncthreads();
    for (int off = 128; off > 0; off >>= 1) {
        if (t < off) lds[t] += lds[t + off];
        __syncthreads();
    }
    if (t == 0) boff_s = lds[0];
    __syncthreads();
    int boff = boff_s;

    int base = b * 1024 + t * 4;
    int d[4]; int s = 0;
#pragma unroll
    for (int j = 0; j < 4; j++) { int i = base + j; d[j] = (i < NN) ? deg[i] : 0; s += d[j]; }
    __syncthreads();
    lds[t] = s;
    __syncthreads();
    for (int off = 1; off < 256; off <<= 1) {
        int u = (t >= off) ? lds[t - off] : 0;
        __syncthreads();
        lds[t] += u;
        __syncthreads();
    }
    int offr = boff + ((t == 0) ? 0 : lds[t - 1]);
#pragma unroll
    for (int j = 0; j < 4; j++) {
        int i = base + j;
        if (i < NN) { row_start[i] = offr; offr += d[j]; }
    }
    if (b == 0 && t == 0) row_start[NN] = NE;
}

// Phase 2b: per-bucket scatter into CSR via LDS cursors.
__global__ __launch_bounds__(256) void csrfill_kernel(const int* __restrict__ gcnt,
                                                      const int* __restrict__ bucketbuf,
                                                      const int* __restrict__ row_start,
                                                      int* __restrict__ csr) {
    __shared__ int cur[256];
    int t = threadIdx.x, b = blockIdx.x;
    int node = b * 256 + t;
    cur[t] = (node < NN) ? row_start[node] : 0;
    __syncthreads();
    int n = gcnt[b * 16]; if (n > BCAP) n = BCAP;
    for (int i = t; i < n; i += 256) {
        int v = bucketbuf[(size_t)b * BCAP + i];
        int pos = atomicAdd(&cur[v & 255], 1);
        csr[pos] = v >> 8;
    }
}

// H[N,F] = fp16( dinv[r] * (X[N,128] @ W[128,F]) ).  fp32 vector GEMM, W in LDS.
// Output packed fp16: halves agg's compulsory per-XCD fetch (the R5 lesson:
// random gather traffic = rowbytes x 8 XCDs, only row size cuts it).
template <int F>
__global__ __launch_bounds__(256) void gemm_kernel(const float* __restrict__ X,
                                                   const float* __restrict__ W,
                                                   const float* __restrict__ dinv,
                                                   __half* __restrict__ H, int N) {
    constexpr int K = 128;
    constexpr int CQ = F / 4;
    constexpr int RS = 256 / CQ;
    constexpr int ROWS = RS * 4;
    __shared__ float Wlds[K * F];
    for (int i = threadIdx.x; i < K * F / 4; i += 256)
        ((float4*)Wlds)[i] = ((const float4*)W)[i];
    __syncthreads();

    int c = (threadIdx.x % CQ) * 4;
    int r0 = blockIdx.x * ROWS + (threadIdx.x / CQ) * 4;
    float4 acc[4];
#pragma unroll
    for (int i = 0; i < 4; i++) acc[i] = make_float4(0.f, 0.f, 0.f, 0.f);

    for (int k = 0; k < K; k += 4) {
        float4 xv[4];
#pragma unroll
        for (int i = 0; i < 4; i++) {
            int rr = r0 + i; if (rr >= N) rr = N - 1;
            xv[i] = *(const float4*)&X[(size_t)rr * K + k];
        }
#pragma unroll
        for (int j = 0; j < 4; j++) {
            float4 wv = *(const float4*)&Wlds[(k + j) * F + c];
#pragma unroll
            for (int i = 0; i < 4; i++) {
                float xk = ((const float*)&xv[i])[j];
                acc[i] = f4_fma(xk, wv, acc[i]);
            }
        }
    }
#pragma unroll
    for (int i = 0; i < 4; i++) {
        int rr = r0 + i;
        if (rr < N) {
            float dv = dinv[rr];
            float4 o = make_float4(dv * acc[i].x, dv * acc[i].y, dv * acc[i].z, dv * acc[i].w);
            *(uint2*)&H[(size_t)rr * F + c] = pack4half(o);
        }
    }
}

// Hs fp16, pre-scaled by dinv[row]. Accumulate fp32.
// OUT[n] = (relu?)( b + dn * (Hs[n] + sum_e Hs[src]) )   OUT is fp32.
template <int F, bool RELU>
__global__ __launch_bounds__(256) void agg_kernel(const __half* __restrict__ Hs,
                                                  const int* __restrict__ rs,
                                                  const int* __restrict__ csr,
                                                  const float* __restrict__ dinv,
                                                  const float* __restrict__ bias,
                                                  float* __restrict__ OUT) {
    constexpr int CQ = F / 8;           // threads per node, 8 cols (16 B) each
    constexpr int NPB = 256 / CQ;
    int node = blockIdx.x * NPB + threadIdx.x / CQ;
    int q = (threadIdx.x % CQ) * 8;
    if (node >= NN) return;
    float dn = dinv[node];
    float acc[8];
    {   // self loop term
        F4H8 u; u.f4 = *(const float4*)&Hs[(size_t)node * F + q];
#pragma unroll
        for (int j = 0; j < 4; j++) {
            float2 f = __half22float2(u.h2[j]);
            acc[2 * j] = f.x; acc[2 * j + 1] = f.y;
        }
    }
    int e = rs[node];
    int e1 = rs[node + 1];
    for (; e + 8 <= e1; e += 8) {
        int s[8];
#pragma unroll
        for (int j = 0; j < 8; j++) s[j] = csr[e + j];
        F4H8 h[8];
#pragma unroll
        for (int j = 0; j < 8; j++) h[j].f4 = *(const float4*)&Hs[(size_t)s[j] * F + q];
#pragma unroll
        for (int j = 0; j < 8; j++) {
#pragma unroll
            for (int k = 0; k < 4; k++) {
                float2 f = __half22float2(h[j].h2[k]);
                acc[2 * k] += f.x; acc[2 * k + 1] += f.y;
            }
        }
    }
    for (; e < e1; e++) {
        int s = csr[e];
        F4H8 u; u.f4 = *(const float4*)&Hs[(size_t)s * F + q];
#pragma unroll
        for (int k = 0; k < 4; k++) {
            float2 f = __half22float2(u.h2[k]);
            acc[2 * k] += f.x; acc[2 * k + 1] += f.y;
        }
    }
    float4 b0 = *(const float4*)&bias[q];
    float4 b1 = *(const float4*)&bias[q + 4];
    float4 o0 = make_float4(dn * acc[0] + b0.x, dn * acc[1] + b0.y,
                            dn * acc[2] + b0.z, dn * acc[3] + b0.w);
    float4 o1 = make_float4(dn * acc[4] + b1.x, dn * acc[5] + b1.y,
                            dn * acc[6] + b1.z, dn * acc[7] + b1.w);
    if (RELU) {
        o0.x = fmaxf(o0.x, 0.f); o0.y = fmaxf(o0.y, 0.f);
        o0.z = fmaxf(o0.z, 0.f); o0.w = fmaxf(o0.w, 0.f);
        o1.x = fmaxf(o1.x, 0.f); o1.y = fmaxf(o1.y, 0.f);
        o1.z = fmaxf(o1.z, 0.f); o1.w = fmaxf(o1.w, 0.f);
    }
    *(float4*)&OUT[(size_t)node * F + q] = o0;
    *(float4*)&OUT[(size_t)node * F + q + 4] = o1;
}

extern "C" void kernel_launch(void* const* d_in, const int* in_sizes, int n_in,
                              void* d_out, int out_size, void* d_ws, size_t ws_size,
                              hipStream_t stream) {
    const float* x  = (const float*)d_in[0];
    const void* eidx = d_in[1];
    const float* W1 = (const float*)d_in[2];
    const float* b1 = (const float*)d_in[3];
    const float* W2 = (const float*)d_in[4];
    const float* b2 = (const float*)d_in[5];
    const float* W3 = (const float*)d_in[6];
    const float* b3 = (const float*)d_in[7];
    float* out = (float*)d_out;

    char* ws = (char*)d_ws;
    size_t off = 0;
    auto alloc = [&](size_t bytes) -> void* {
        void* p = ws + off;
        off += (bytes + 255) & ~(size_t)255;
        return p;
    };
    // bufB (fp32, 51.2 MB) overlaps deg/blocksum (dead before agg1 writes bufB);
    // bufH (fp16, 25.6 MB) overlaps bucketbuf/gcnt (dead before gemm1 writes bufH).
    float* bufB = (float*)alloc((size_t)NN * 128 * 4);
    int* deg      = (int*)bufB;                                  // NN ints
    int* blocksum = (int*)((char*)bufB + (size_t)NN * 4);        // SCAN_BLOCKS ints
    int* row_start = (int*)alloc((size_t)(NN + 1) * 4);
    float* dinv = (float*)alloc((size_t)NN * 4);
    int* flagp  = (int*)alloc(256);
    int* csr    = (int*)alloc((size_t)NE * 4);
    __half* bufH = (__half*)alloc((size_t)NN * 128 * 2);
    int* bucketbuf = (int*)bufH;                                    // NBK*BCAP ints (7.2MB)
    int* gcnt      = (int*)((char*)bufH + (size_t)NBK * BCAP * 4);  // NBK*16 ints, line-padded

    hipMemsetAsync(gcnt, 0, (size_t)NBK * 16 * 4, stream);
    detect_flag_kernel<<<1, 256, 0, stream>>>((const int*)eidx, flagp);
    bin_kernel<<<BIN_BLOCKS, 256, 0, stream>>>(eidx, flagp, gcnt, bucketbuf);
    hist_kernel<<<NBK, 256, 0, stream>>>(gcnt, bucketbuf, deg);
    dinv_kernel<<<(NN + 255) / 256, 256, 0, stream>>>(deg, dinv);
    scanA_kernel<<<SCAN_BLOCKS, 256, 0, stream>>>(deg, blocksum);
    scanC_kernel<<<SCAN_BLOCKS, 256, 0, stream>>>(deg, blocksum, row_start);
    csrfill_kernel<<<NBK, 256, 0, stream>>>(gcnt, bucketbuf, row_start, csr);

    // Layer 1
    gemm_kernel<128><<<NN / 32, 256, 0, stream>>>(x, W1, dinv, bufH, NN);
    agg_kernel<128, true><<<NN / 16, 256, 0, stream>>>(bufH, row_start, csr, dinv, b1, bufB);
    // Layer 2
    gemm_kernel<128><<<NN / 32, 256, 0, stream>>>(bufB, W2, dinv, bufH, NN);
    agg_kernel<128, true><<<NN / 16, 256, 0, stream>>>(bufH, row_start, csr, dinv, b2, bufB);
    // Layer 3 (128 -> 64, no relu)
    gemm_kernel<64><<<(NN + 63) / 64, 256, 0, stream>>>(bufB, W3, dinv, bufH, NN);
    agg_kernel<64, false><<<NN / 32, 256, 0, stream>>>(bufH, row_start, csr, dinv, b3, out);
}

// Round 7
// 426.898 us; speedup vs baseline: 2.3482x; 1.2403x over previous
//
#include <hip/hip_runtime.h>
#include <hip/hip_fp16.h>
#include <cstdint>
#include <cstddef>
#include <type_traits>

#define NN 100000
#define NE 1600000
#define SCAN_BLOCKS ((NN + 1023) / 1024)   // 98
#define NBK ((NN + 255) / 256)             // 391 dst-buckets of 256 nodes
#define BCAP 4608                          // mean 4092, std ~64 -> 8 sigma slack
#define EPB 4096                           // edges per bin block
#define BIN_BLOCKS ((NE + EPB - 1) / EPB)  // 391

using half8 = __attribute__((ext_vector_type(8))) _Float16;
using f32x4 = __attribute__((ext_vector_type(4))) float;

union F4H8 { float4 f4; __half2 h2[4]; };  // 16 B = 8 halves

__device__ __forceinline__ uint2 pack4half(float4 v) {
    __half2 a = __floats2half2_rn(v.x, v.y);
    __half2 b = __floats2half2_rn(v.z, v.w);
    uint2 r;
    r.x = *(unsigned int*)&a;
    r.y = *(unsigned int*)&b;
    return r;
}

// ---------------- edge-index detection ----------------
__global__ void detect_flag_kernel(const int* __restrict__ idx, int* __restrict__ flag) {
    __shared__ int cnt;
    if (threadIdx.x == 0) cnt = 0;
    __syncthreads();
    if (idx[2 * threadIdx.x + 1] == 0) atomicAdd(&cnt, 1);
    __syncthreads();
    if (threadIdx.x == 0) *flag = (cnt == (int)blockDim.x) ? 1 : 0;
}

// ---------------- CSR build (R5 structure, unchanged) ----------------
__global__ __launch_bounds__(256) void bin_kernel(const void* __restrict__ idx,
                                                  const int* __restrict__ flag,
                                                  int* __restrict__ gcnt,       // NBK, stride 16
                                                  int* __restrict__ bucketbuf) {
    __shared__ int cnt[NBK];
    __shared__ int gbase[NBK];
    int t = threadIdx.x;
    long long base = (long long)blockIdx.x * EPB;
    for (int i = t; i < NBK; i += 256) cnt[i] = 0;
    __syncthreads();
    bool is64 = (*flag != 0);
    int lpos[16];
#pragma unroll
    for (int j = 0; j < 16; j++) {
        long long e = base + j * 256 + t;
        lpos[j] = 0;
        if (e < NE) {
            int d_ = is64 ? (int)((const long long*)idx)[NE + e]
                          : ((const int*)idx)[NE + e];
            lpos[j] = atomicAdd(&cnt[d_ >> 8], 1);
        }
    }
    __syncthreads();
    for (int b = t; b < NBK; b += 256) {
        int c = cnt[b];
        gbase[b] = (c > 0) ? atomicAdd(&gcnt[b * 16], c) : 0;
    }
    __syncthreads();
#pragma unroll
    for (int j = 0; j < 16; j++) {
        long long e = base + j * 256 + t;
        if (e < NE) {
            int s_, d_;
            if (is64) { const long long* p = (const long long*)idx; s_ = (int)p[e]; d_ = (int)p[NE + e]; }
            else      { const int* p = (const int*)idx;             s_ = p[e];      d_ = p[NE + e]; }
            int b = d_ >> 8;
            int pos = gbase[b] + lpos[j];
            if (pos < BCAP) bucketbuf[(size_t)b * BCAP + pos] = (s_ << 8) | (d_ & 255);
        }
    }
}

__global__ __launch_bounds__(256) void hist_kernel(const int* __restrict__ gcnt,
                                                   const int* __restrict__ bucketbuf,
                                                   int* __restrict__ deg) {
    __shared__ int cnt[256];
    int t = threadIdx.x, b = blockIdx.x;
    cnt[t] = 0;
    __syncthreads();
    int n = gcnt[b * 16]; if (n > BCAP) n = BCAP;
    for (int i = t; i < n; i += 256)
        atomicAdd(&cnt[bucketbuf[(size_t)b * BCAP + i] & 255], 1);
    __syncthreads();
    int node = b * 256 + t;
    if (node < NN) deg[node] = cnt[t];
}

__global__ void dinv_kernel(const int* __restrict__ deg, float* __restrict__ dinv) {
    int n = blockIdx.x * blockDim.x + threadIdx.x;
    if (n < NN) dinv[n] = rsqrtf((float)(deg[n] + 1));  // +1 self loop
}

__global__ __launch_bounds__(256) void scanA_kernel(const int* __restrict__ deg,
                                                    int* __restrict__ blocksum) {
    __shared__ int red[256];
    int t = threadIdx.x;
    int base = blockIdx.x * 1024 + t * 4;
    int s = 0;
#pragma unroll
    for (int j = 0; j < 4; j++) { int i = base + j; if (i < NN) s += deg[i]; }
    red[t] = s;
    __syncthreads();
    for (int off = 128; off > 0; off >>= 1) {
        if (t < off) red[t] += red[t + off];
        __syncthreads();
    }
    if (t == 0) blocksum[blockIdx.x] = red[0];
}

__global__ __launch_bounds__(256) void scanC_kernel(const int* __restrict__ deg,
                                                    const int* __restrict__ blocksum,
                                                    int* __restrict__ row_start) {
    __shared__ int lds[256];
    __shared__ int boff_s;
    int t = threadIdx.x;
    int b = blockIdx.x;
    lds[t] = (t < b && t < SCAN_BLOCKS) ? blocksum[t] : 0;
    __syncthreads();
    for (int off = 128; off > 0; off >>= 1) {
        if (t < off) lds[t] += lds[t + off];
        __syncthreads();
    }
    if (t == 0) boff_s = lds[0];
    __syncthreads();
    int boff = boff_s;

    int base = b * 1024 + t * 4;
    int d[4]; int s = 0;
#pragma unroll
    for (int j = 0; j < 4; j++) { int i = base + j; d[j] = (i < NN) ? deg[i] : 0; s += d[j]; }
    __syncthreads();
    lds[t] = s;
    __syncthreads();
    for (int off = 1; off < 256; off <<= 1) {
        int u = (t >= off) ? lds[t - off] : 0;
        __syncthreads();
        lds[t] += u;
        __syncthreads();
    }
    int offr = boff + ((t == 0) ? 0 : lds[t - 1]);
#pragma unroll
    for (int j = 0; j < 4; j++) {
        int i = base + j;
        if (i < NN) { row_start[i] = offr; offr += d[j]; }
    }
    if (b == 0 && t == 0) row_start[NN] = NE;
}

__global__ __launch_bounds__(256) void csrfill_kernel(const int* __restrict__ gcnt,
                                                      const int* __restrict__ bucketbuf,
                                                      const int* __restrict__ row_start,
                                                      int* __restrict__ csr) {
    __shared__ int cur[256];
    int t = threadIdx.x, b = blockIdx.x;
    int node = b * 256 + t;
    cur[t] = (node < NN) ? row_start[node] : 0;
    __syncthreads();
    int n = gcnt[b * 16]; if (n > BCAP) n = BCAP;
    for (int i = t; i < n; i += 256) {
        int v = bucketbuf[(size_t)b * BCAP + i];
        int pos = atomicAdd(&cur[v & 255], 1);
        csr[pos] = v >> 8;
    }
}

// ---------------- conversions ----------------
// Wt[n][k] = fp16(W[k][n])  (transposed so B-fragments are 16B-contiguous)
__global__ void wt_kernel(const float* __restrict__ W, __half* __restrict__ Wt, int F) {
    int i = blockIdx.x * 256 + threadIdx.x;
    if (i >= 128 * F) return;
    int k = i / F, n = i % F;
    Wt[(size_t)n * 128 + k] = __float2half(W[i]);
}

// Xh = fp16(x), row-major [NN,128]
__global__ void xh_kernel(const float* __restrict__ X, __half* __restrict__ Xh) {
    int i = blockIdx.x * 256 + threadIdx.x;
    if (i >= NN * 128 / 4) return;
    float4 v = ((const float4*)X)[i];
    *(uint2*)&Xh[(size_t)i * 4] = pack4half(v);
}

// ---------------- MFMA GEMM ----------------
// H[N,F] = fp16( dinv[r] * (A[N,128] @ W[128,F]) ), A fp16, Wt=[F][128] fp16.
// Wave: 16 rows x F cols; block: 4 waves = 64 rows. No main-loop LDS;
// B-frags re-read from global Wt (32KB, L1-resident). Epilogue via padded LDS.
template <int F>
__global__ __launch_bounds__(256) void mfma_gemm_kernel(const __half* __restrict__ A,
                                                        const __half* __restrict__ Wt,
                                                        const float* __restrict__ dinv,
                                                        __half* __restrict__ H, int N) {
    constexpr int K = 128;
    constexpr int NT = F / 16;          // n-tiles per wave
    constexpr int FP = F + 8;           // padded LDS row stride (halves)
    __shared__ __half hs[64 * FP];

    int wave = threadIdx.x >> 6;
    int lane = threadIdx.x & 63;
    int quad = lane >> 4;
    int l16  = lane & 15;
    int rowbase = blockIdx.x * 64 + wave * 16;
    int arow = rowbase + l16; if (arow >= N) arow = N - 1;

    // A-fragments: A[m=l16][k=quad*8+j+32*s]
    half8 afrag[4];
    const __half* ap = A + (size_t)arow * K + quad * 8;
#pragma unroll
    for (int s = 0; s < 4; s++) afrag[s] = *(const half8*)(ap + s * 32);

    f32x4 acc[NT];
#pragma unroll
    for (int t = 0; t < NT; t++) acc[t] = (f32x4){0.f, 0.f, 0.f, 0.f};

#pragma unroll
    for (int s = 0; s < 4; s++) {
#pragma unroll
        for (int t = 0; t < NT; t++) {
            // B[k=quad*8+j+32*s][n=t*16+l16] from Wt[n][k]
            half8 b = *(const half8*)(Wt + (size_t)(t * 16 + l16) * K + s * 32 + quad * 8);
            acc[t] = __builtin_amdgcn_mfma_f32_16x16x32_f16(afrag[s], b, acc[t], 0, 0, 0);
        }
    }

    // C/D: col=l16, row=quad*4+r  ->  hs[wave*16 + quad*4 + r][t*16 + l16]
    float dv[4];
#pragma unroll
    for (int r = 0; r < 4; r++) {
        int grow = rowbase + quad * 4 + r;
        dv[r] = (grow < N) ? dinv[grow] : 0.f;
    }
#pragma unroll
    for (int t = 0; t < NT; t++) {
#pragma unroll
        for (int r = 0; r < 4; r++) {
            int lrow = wave * 16 + quad * 4 + r;
            hs[lrow * FP + t * 16 + l16] = __float2half(acc[t][r] * dv[r]);
        }
    }
    __syncthreads();
    constexpr int CHUNKS = 64 * F / 8;   // 16B chunks
    for (int i = threadIdx.x; i < CHUNKS; i += 256) {
        int row = i / (F / 8);
        int col8 = (i % (F / 8)) * 8;
        int grow = blockIdx.x * 64 + row;
        if (grow < N)
            *(uint4*)&H[(size_t)grow * F + col8] = *(const uint4*)&hs[row * FP + col8];
    }
}

// ---------------- aggregation (gather) ----------------
// Hs fp16 pre-scaled by dinv[row]; accumulate fp32.
// OUT[n] = (relu?)( b + dn * (Hs[n] + sum_e Hs[src]) ); OutT = __half or float.
template <int F, bool RELU, typename OutT>
__global__ __launch_bounds__(256) void agg_kernel(const __half* __restrict__ Hs,
                                                  const int* __restrict__ rs,
                                                  const int* __restrict__ csr,
                                                  const float* __restrict__ dinv,
                                                  const float* __restrict__ bias,
                                                  OutT* __restrict__ OUT) {
    constexpr int CQ = F / 8;           // threads per node, 8 cols (16 B) each
    constexpr int NPB = 256 / CQ;
    int node = blockIdx.x * NPB + threadIdx.x / CQ;
    int q = (threadIdx.x % CQ) * 8;
    if (node >= NN) return;
    float dn = dinv[node];
    float acc[8];
    {   // self loop term
        F4H8 u; u.f4 = *(const float4*)&Hs[(size_t)node * F + q];
#pragma unroll
        for (int j = 0; j < 4; j++) {
            float2 f = __half22float2(u.h2[j]);
            acc[2 * j] = f.x; acc[2 * j + 1] = f.y;
        }
    }
    int e = rs[node];
    int e1 = rs[node + 1];
    for (; e + 8 <= e1; e += 8) {
        int s[8];
#pragma unroll
        for (int j = 0; j < 8; j++) s[j] = csr[e + j];
        F4H8 h[8];
#pragma unroll
        for (int j = 0; j < 8; j++) h[j].f4 = *(const float4*)&Hs[(size_t)s[j] * F + q];
#pragma unroll
        for (int j = 0; j < 8; j++) {
#pragma unroll
            for (int k = 0; k < 4; k++) {
                float2 f = __half22float2(h[j].h2[k]);
                acc[2 * k] += f.x; acc[2 * k + 1] += f.y;
            }
        }
    }
    for (; e < e1; e++) {
        int s = csr[e];
        F4H8 u; u.f4 = *(const float4*)&Hs[(size_t)s * F + q];
#pragma unroll
        for (int k = 0; k < 4; k++) {
            float2 f = __half22float2(u.h2[k]);
            acc[2 * k] += f.x; acc[2 * k + 1] += f.y;
        }
    }
    float o[8];
#pragma unroll
    for (int j = 0; j < 8; j++) {
        o[j] = dn * acc[j] + bias[q + j];
        if (RELU) o[j] = fmaxf(o[j], 0.f);
    }
    if constexpr (std::is_same<OutT, float>::value) {
        *(float4*)&OUT[(size_t)node * F + q]     = make_float4(o[0], o[1], o[2], o[3]);
        *(float4*)&OUT[(size_t)node * F + q + 4] = make_float4(o[4], o[5], o[6], o[7]);
    } else {
        uint4 p;
        uint2 a = pack4half(make_float4(o[0], o[1], o[2], o[3]));
        uint2 b = pack4half(make_float4(o[4], o[5], o[6], o[7]));
        p.x = a.x; p.y = a.y; p.z = b.x; p.w = b.y;
        *(uint4*)&OUT[(size_t)node * F + q] = p;
    }
}

extern "C" void kernel_launch(void* const* d_in, const int* in_sizes, int n_in,
                              void* d_out, int out_size, void* d_ws, size_t ws_size,
                              hipStream_t stream) {
    const float* x  = (const float*)d_in[0];
    const void* eidx = d_in[1];
    const float* W1 = (const float*)d_in[2];
    const float* b1 = (const float*)d_in[3];
    const float* W2 = (const float*)d_in[4];
    const float* b2 = (const float*)d_in[5];
    const float* W3 = (const float*)d_in[6];
    const float* b3 = (const float*)d_in[7];
    float* out = (float*)d_out;

    char* ws = (char*)d_ws;
    size_t off = 0;
    auto alloc = [&](size_t bytes) -> void* {
        void* p = ws + off;
        off += (bytes + 255) & ~(size_t)255;
        return p;
    };
    // bufB (fp16 activations, 25.6 MB) overlays deg/blocksum (dead before agg1);
    // bufH (fp16 gather array, 25.6 MB) overlays bucketbuf/gcnt (dead before gemm1).
    __half* bufB = (__half*)alloc((size_t)NN * 128 * 2);
    int* deg      = (int*)bufB;                                  // NN ints
    int* blocksum = (int*)((char*)bufB + (size_t)NN * 4);        // SCAN_BLOCKS ints
    int* row_start = (int*)alloc((size_t)(NN + 1) * 4);
    float* dinv = (float*)alloc((size_t)NN * 4);
    int* flagp  = (int*)alloc(256);
    int* csr    = (int*)alloc((size_t)NE * 4);
    __half* bufH = (__half*)alloc((size_t)NN * 128 * 2);
    int* bucketbuf = (int*)bufH;                                    // NBK*BCAP ints (7.2MB)
    int* gcnt      = (int*)((char*)bufH + (size_t)NBK * BCAP * 4);  // NBK*16 ints, padded
    __half* Xh  = (__half*)alloc((size_t)NN * 128 * 2);
    __half* Wt1 = (__half*)alloc((size_t)128 * 128 * 2);
    __half* Wt2 = (__half*)alloc((size_t)128 * 128 * 2);
    __half* Wt3 = (__half*)alloc((size_t)64 * 128 * 2);

    hipMemsetAsync(gcnt, 0, (size_t)NBK * 16 * 4, stream);
    detect_flag_kernel<<<1, 256, 0, stream>>>((const int*)eidx, flagp);
    bin_kernel<<<BIN_BLOCKS, 256, 0, stream>>>(eidx, flagp, gcnt, bucketbuf);
    hist_kernel<<<NBK, 256, 0, stream>>>(gcnt, bucketbuf, deg);
    dinv_kernel<<<(NN + 255) / 256, 256, 0, stream>>>(deg, dinv);
    scanA_kernel<<<SCAN_BLOCKS, 256, 0, stream>>>(deg, blocksum);
    scanC_kernel<<<SCAN_BLOCKS, 256, 0, stream>>>(deg, blocksum, row_start);
    csrfill_kernel<<<NBK, 256, 0, stream>>>(gcnt, bucketbuf, row_start, csr);

    wt_kernel<<<(128 * 128 + 255) / 256, 256, 0, stream>>>(W1, Wt1, 128);
    wt_kernel<<<(128 * 128 + 255) / 256, 256, 0, stream>>>(W2, Wt2, 128);
    wt_kernel<<<(128 * 64 + 255) / 256, 256, 0, stream>>>(W3, Wt3, 64);
    xh_kernel<<<(NN * 128 / 4 + 255) / 256, 256, 0, stream>>>(x, Xh);

    const int GB = (NN + 63) / 64;   // 1563 gemm blocks
    // Layer 1
    mfma_gemm_kernel<128><<<GB, 256, 0, stream>>>(Xh, Wt1, dinv, bufH, NN);
    agg_kernel<128, true, __half><<<NN / 16, 256, 0, stream>>>(bufH, row_start, csr, dinv, b1, bufB);
    // Layer 2
    mfma_gemm_kernel<128><<<GB, 256, 0, stream>>>(bufB, Wt2, dinv, bufH, NN);
    agg_kernel<128, true, __half><<<NN / 16, 256, 0, stream>>>(bufH, row_start, csr, dinv, b2, bufB);
    // Layer 3 (128 -> 64, no relu, fp32 out)
    mfma_gemm_kernel<64><<<GB, 256, 0, stream>>>(bufB, Wt3, dinv, bufH, NN);
    agg_kernel<64, false, float><<<NN / 32, 256, 0, stream>>>(bufH, row_start, csr, dinv, b3, out);
}

// Round 8
// 424.825 us; speedup vs baseline: 2.3596x; 1.0049x over previous
//
#include <hip/hip_runtime.h>
#include <hip/hip_fp16.h>
#include <cstdint>
#include <cstddef>
#include <type_traits>

#define NN 100000
#define NE 1600000
#define SCAN_BLOCKS ((NN + 1023) / 1024)   // 98
#define NBK ((NN + 255) / 256)             // 391 dst-buckets of 256 nodes
#define BCAP 4608                          // mean 4092, std ~64 -> 8 sigma slack
#define EPB 4096                           // edges per bin block
#define BIN_BLOCKS ((NE + EPB - 1) / EPB)  // 391
#define SBINS 64                           // degree-sort bins (deg clamped to 63)

using half8 = __attribute__((ext_vector_type(8))) _Float16;
using f32x4 = __attribute__((ext_vector_type(4))) float;

union F4H8 { float4 f4; __half2 h2[4]; };  // 16 B = 8 halves

__device__ __forceinline__ uint2 pack4half(float4 v) {
    __half2 a = __floats2half2_rn(v.x, v.y);
    __half2 b = __floats2half2_rn(v.z, v.w);
    uint2 r;
    r.x = *(unsigned int*)&a;
    r.y = *(unsigned int*)&b;
    return r;
}

// ---------------- edge-index detection ----------------
__global__ void detect_flag_kernel(const int* __restrict__ idx, int* __restrict__ flag) {
    __shared__ int cnt;
    if (threadIdx.x == 0) cnt = 0;
    __syncthreads();
    if (idx[2 * threadIdx.x + 1] == 0) atomicAdd(&cnt, 1);
    __syncthreads();
    if (threadIdx.x == 0) *flag = (cnt == (int)blockDim.x) ? 1 : 0;
}

// ---------------- CSR build ----------------
__global__ __launch_bounds__(256) void bin_kernel(const void* __restrict__ idx,
                                                  const int* __restrict__ flag,
                                                  int* __restrict__ gcnt,       // NBK, stride 16
                                                  int* __restrict__ bucketbuf) {
    __shared__ int cnt[NBK];
    __shared__ int gbase[NBK];
    int t = threadIdx.x;
    long long base = (long long)blockIdx.x * EPB;
    for (int i = t; i < NBK; i += 256) cnt[i] = 0;
    __syncthreads();
    bool is64 = (*flag != 0);
    int lpos[16], d16[16];
#pragma unroll
    for (int j = 0; j < 16; j++) {
        long long e = base + j * 256 + t;
        lpos[j] = 0; d16[j] = 0;
        if (e < NE) {
            int d_ = is64 ? (int)((const long long*)idx)[NE + e]
                          : ((const int*)idx)[NE + e];
            d16[j] = d_;
            lpos[j] = atomicAdd(&cnt[d_ >> 8], 1);
        }
    }
    __syncthreads();
    for (int b = t; b < NBK; b += 256) {
        int c = cnt[b];
        gbase[b] = (c > 0) ? atomicAdd(&gcnt[b * 16], c) : 0;
    }
    __syncthreads();
#pragma unroll
    for (int j = 0; j < 16; j++) {
        long long e = base + j * 256 + t;
        if (e < NE) {
            int s_ = is64 ? (int)((const long long*)idx)[e] : ((const int*)idx)[e];
            int d_ = d16[j];
            int b = d_ >> 8;
            int pos = gbase[b] + lpos[j];
            if (pos < BCAP) bucketbuf[(size_t)b * BCAP + pos] = (s_ << 8) | (d_ & 255);
        }
    }
}

// Per-bucket LDS histogram -> deg + dinv + degree-sort bin counts.
__global__ __launch_bounds__(256) void hist_kernel(const int* __restrict__ gcnt,
                                                   const int* __restrict__ bucketbuf,
                                                   int* __restrict__ deg,
                                                   float* __restrict__ dinv,
                                                   int* __restrict__ scnt) {  // SBINS*16 padded
    __shared__ int cnt[256];
    __shared__ int sh[SBINS];
    int t = threadIdx.x, b = blockIdx.x;
    cnt[t] = 0;
    if (t < SBINS) sh[t] = 0;
    __syncthreads();
    int n = gcnt[b * 16]; if (n > BCAP) n = BCAP;
    for (int i = t; i < n; i += 256)
        atomicAdd(&cnt[bucketbuf[(size_t)b * BCAP + i] & 255], 1);
    __syncthreads();
    int node = b * 256 + t;
    if (node < NN) {
        int d = cnt[t];
        deg[node] = d;
        dinv[node] = rsqrtf((float)(d + 1));   // +1 self loop
        atomicAdd(&sh[d < SBINS ? d : SBINS - 1], 1);
    }
    __syncthreads();
    if (t < SBINS && sh[t] > 0) atomicAdd(&scnt[t * 16], sh[t]);
}

__global__ __launch_bounds__(256) void scanA_kernel(const int* __restrict__ deg,
                                                    int* __restrict__ blocksum) {
    __shared__ int red[256];
    int t = threadIdx.x;
    int base = blockIdx.x * 1024 + t * 4;
    int s = 0;
#pragma unroll
    for (int j = 0; j < 4; j++) { int i = base + j; if (i < NN) s += deg[i]; }
    red[t] = s;
    __syncthreads();
    for (int off = 128; off > 0; off >>= 1) {
        if (t < off) red[t] += red[t + off];
        __syncthreads();
    }
    if (t == 0) blocksum[blockIdx.x] = red[0];
}

__global__ __launch_bounds__(256) void scanC_kernel(const int* __restrict__ deg,
                                                    const int* __restrict__ blocksum,
                                                    int* __restrict__ row_start) {
    __shared__ int lds[256];
    __shared__ int boff_s;
    int t = threadIdx.x;
    int b = blockIdx.x;
    lds[t] = (t < b && t < SCAN_BLOCKS) ? blocksum[t] : 0;
    __syncthreads();
    for (int off = 128; off > 0; off >>= 1) {
        if (t < off) lds[t] += lds[t + off];
        __syncthreads();
    }
    if (t == 0) boff_s = lds[0];
    __syncthreads();
    int boff = boff_s;

    int base = b * 1024 + t * 4;
    int d[4]; int s = 0;
#pragma unroll
    for (int j = 0; j < 4; j++) { int i = base + j; d[j] = (i < NN) ? deg[i] : 0; s += d[j]; }
    __syncthreads();
    lds[t] = s;
    __syncthreads();
    for (int off = 1; off < 256; off <<= 1) {
        int u = (t >= off) ? lds[t - off] : 0;
        __syncthreads();
        lds[t] += u;
        __syncthreads();
    }
    int offr = boff + ((t == 0) ? 0 : lds[t - 1]);
#pragma unroll
    for (int j = 0; j < 4; j++) {
        int i = base + j;
        if (i < NN) { row_start[i] = offr; offr += d[j]; }
    }
    if (b == 0 && t == 0) row_start[NN] = NE;
}

__global__ __launch_bounds__(256) void csrfill_kernel(const int* __restrict__ gcnt,
                                                      const int* __restrict__ bucketbuf,
                                                      const int* __restrict__ row_start,
                                                      int* __restrict__ csr) {
    __shared__ int cur[256];
    int t = threadIdx.x, b = blockIdx.x;
    int node = b * 256 + t;
    cur[t] = (node < NN) ? row_start[node] : 0;
    __syncthreads();
    int n = gcnt[b * 16]; if (n > BCAP) n = BCAP;
    for (int i = t; i < n; i += 256) {
        int v = bucketbuf[(size_t)b * BCAP + i];
        int pos = atomicAdd(&cur[v & 255], 1);
        csr[pos] = v >> 8;
    }
}

// ---------------- degree sort (counting sort) ----------------
__global__ void sort_scan_kernel(const int* __restrict__ scnt, int* __restrict__ sbase) {
    if (threadIdx.x == 0) {
        int acc = 0;
        for (int i = 0; i < SBINS; i++) { sbase[i * 16] = acc; acc += scnt[i * 16]; }
    }
}

// Scatter nodes into degree-sorted order via per-block bulk reservation.
__global__ __launch_bounds__(256) void order_kernel(const int* __restrict__ deg,
                                                    int* __restrict__ sbase,   // cursors, stride 16
                                                    int* __restrict__ order) {
    __shared__ int lcnt[SBINS];
    __shared__ int lbase[SBINS];
    int t = threadIdx.x;
    if (t < SBINS) lcnt[t] = 0;
    __syncthreads();
    int node = blockIdx.x * 256 + t;
    int bin = 0, lpos = 0;
    bool valid = node < NN;
    if (valid) {
        int d = deg[node];
        bin = d < SBINS ? d : SBINS - 1;
        lpos = atomicAdd(&lcnt[bin], 1);
    }
    __syncthreads();
    if (t < SBINS) {
        int c = lcnt[t];
        lbase[t] = (c > 0) ? atomicAdd(&sbase[t * 16], c) : 0;
    }
    __syncthreads();
    if (valid) order[lbase[bin] + lpos] = node;
}

// ---------------- conversions ----------------
__global__ void wt_kernel(const float* __restrict__ W, __half* __restrict__ Wt, int F) {
    int i = blockIdx.x * 256 + threadIdx.x;
    if (i >= 128 * F) return;
    int k = i / F, n = i % F;
    Wt[(size_t)n * 128 + k] = __float2half(W[i]);
}

// ---------------- MFMA GEMM ----------------
// H[N,F] = fp16( dinv[r] * (A[N,128] @ W[128,F]) ); A fp16 or fp32 (converted
// in-register, saving the standalone conversion pass). Wt=[F][128] fp16.
template <int F, typename AT>
__global__ __launch_bounds__(256) void mfma_gemm_kernel(const AT* __restrict__ A,
                                                        const __half* __restrict__ Wt,
                                                        const float* __restrict__ dinv,
                                                        __half* __restrict__ H, int N) {
    constexpr int K = 128;
    constexpr int NT = F / 16;
    constexpr int FP = F + 8;
    __shared__ __half hs[64 * FP];

    int wave = threadIdx.x >> 6;
    int lane = threadIdx.x & 63;
    int quad = lane >> 4;
    int l16  = lane & 15;
    int rowbase = blockIdx.x * 64 + wave * 16;
    int arow = rowbase + l16; if (arow >= N) arow = N - 1;

    half8 afrag[4];
    const AT* ap = A + (size_t)arow * K + quad * 8;
#pragma unroll
    for (int s = 0; s < 4; s++) {
        if constexpr (std::is_same<AT, float>::value) {
            float4 u0 = *(const float4*)(ap + s * 32);
            float4 u1 = *(const float4*)(ap + s * 32 + 4);
            half8 h;
            h[0] = (_Float16)u0.x; h[1] = (_Float16)u0.y;
            h[2] = (_Float16)u0.z; h[3] = (_Float16)u0.w;
            h[4] = (_Float16)u1.x; h[5] = (_Float16)u1.y;
            h[6] = (_Float16)u1.z; h[7] = (_Float16)u1.w;
            afrag[s] = h;
        } else {
            afrag[s] = *(const half8*)(ap + s * 32);
        }
    }

    f32x4 acc[NT];
#pragma unroll
    for (int t = 0; t < NT; t++) acc[t] = (f32x4){0.f, 0.f, 0.f, 0.f};

#pragma unroll
    for (int s = 0; s < 4; s++) {
#pragma unroll
        for (int t = 0; t < NT; t++) {
            half8 b = *(const half8*)(Wt + (size_t)(t * 16 + l16) * K + s * 32 + quad * 8);
            acc[t] = __builtin_amdgcn_mfma_f32_16x16x32_f16(afrag[s], b, acc[t], 0, 0, 0);
        }
    }

    // C/D: col=l16, row=quad*4+r
    float dv[4];
#pragma unroll
    for (int r = 0; r < 4; r++) {
        int grow = rowbase + quad * 4 + r;
        dv[r] = (grow < N) ? dinv[grow] : 0.f;
    }
#pragma unroll
    for (int t = 0; t < NT; t++) {
#pragma unroll
        for (int r = 0; r < 4; r++) {
            int lrow = wave * 16 + quad * 4 + r;
            hs[lrow * FP + t * 16 + l16] = __float2half(acc[t][r] * dv[r]);
        }
    }
    __syncthreads();
    constexpr int CHUNKS = 64 * F / 8;
    for (int i = threadIdx.x; i < CHUNKS; i += 256) {
        int row = i / (F / 8);
        int col8 = (i % (F / 8)) * 8;
        int grow = blockIdx.x * 64 + row;
        if (grow < N)
            *(uint4*)&H[(size_t)grow * F + col8] = *(const uint4*)&hs[row * FP + col8];
    }
}

// ---------------- aggregation (gather) ----------------
// Degree-sorted node order: same-degree nodes share a wave -> no intra-wave
// edge-loop imbalance. Hs fp16 pre-scaled by dinv[row]; accumulate fp32.
template <int F, bool RELU, typename OutT>
__global__ __launch_bounds__(256) void agg_kernel(const __half* __restrict__ Hs,
                                                  const int* __restrict__ order,
                                                  const int* __restrict__ rs,
                                                  const int* __restrict__ csr,
                                                  const float* __restrict__ dinv,
                                                  const float* __restrict__ bias,
                                                  OutT* __restrict__ OUT) {
    constexpr int CQ = F / 8;           // threads per node, 8 cols (16 B) each
    constexpr int NPB = 256 / CQ;
    int idx = blockIdx.x * NPB + threadIdx.x / CQ;
    int q = (threadIdx.x % CQ) * 8;
    if (idx >= NN) return;
    int node = order[idx];
    float dn = dinv[node];
    float acc[8];
    {   // self loop term
        F4H8 u; u.f4 = *(const float4*)&Hs[(size_t)node * F + q];
#pragma unroll
        for (int j = 0; j < 4; j++) {
            float2 f = __half22float2(u.h2[j]);
            acc[2 * j] = f.x; acc[2 * j + 1] = f.y;
        }
    }
    int e = rs[node];
    int e1 = rs[node + 1];
    for (; e + 8 <= e1; e += 8) {
        int s[8];
#pragma unroll
        for (int j = 0; j < 8; j++) s[j] = csr[e + j];
        F4H8 h[8];
#pragma unroll
        for (int j = 0; j < 8; j++) h[j].f4 = *(const float4*)&Hs[(size_t)s[j] * F + q];
#pragma unroll
        for (int j = 0; j < 8; j++) {
#pragma unroll
            for (int k = 0; k < 4; k++) {
                float2 f = __half22float2(h[j].h2[k]);
                acc[2 * k] += f.x; acc[2 * k + 1] += f.y;
            }
        }
    }
    for (; e < e1; e++) {
        int s = csr[e];
        F4H8 u; u.f4 = *(const float4*)&Hs[(size_t)s * F + q];
#pragma unroll
        for (int k = 0; k < 4; k++) {
            float2 f = __half22float2(u.h2[k]);
            acc[2 * k] += f.x; acc[2 * k + 1] += f.y;
        }
    }
    float o[8];
#pragma unroll
    for (int j = 0; j < 8; j++) {
        o[j] = dn * acc[j] + bias[q + j];
        if (RELU) o[j] = fmaxf(o[j], 0.f);
    }
    if constexpr (std::is_same<OutT, float>::value) {
        *(float4*)&OUT[(size_t)node * F + q]     = make_float4(o[0], o[1], o[2], o[3]);
        *(float4*)&OUT[(size_t)node * F + q + 4] = make_float4(o[4], o[5], o[6], o[7]);
    } else {
        uint4 p;
        uint2 a = pack4half(make_float4(o[0], o[1], o[2], o[3]));
        uint2 b = pack4half(make_float4(o[4], o[5], o[6], o[7]));
        p.x = a.x; p.y = a.y; p.z = b.x; p.w = b.y;
        *(uint4*)&OUT[(size_t)node * F + q] = p;
    }
}

extern "C" void kernel_launch(void* const* d_in, const int* in_sizes, int n_in,
                              void* d_out, int out_size, void* d_ws, size_t ws_size,
                              hipStream_t stream) {
    const float* x  = (const float*)d_in[0];
    const void* eidx = d_in[1];
    const float* W1 = (const float*)d_in[2];
    const float* b1 = (const float*)d_in[3];
    const float* W2 = (const float*)d_in[4];
    const float* b2 = (const float*)d_in[5];
    const float* W3 = (const float*)d_in[6];
    const float* b3 = (const float*)d_in[7];
    float* out = (float*)d_out;

    char* ws = (char*)d_ws;
    size_t off = 0;
    auto alloc = [&](size_t bytes) -> void* {
        void* p = ws + off;
        off += (bytes + 255) & ~(size_t)255;
        return p;
    };
    // bufB (fp16, 25.6 MB) overlays deg/blocksum (all CSR/sort reads of deg
    // finish before agg1 writes bufB); bufH overlays bucketbuf/gcnt (dead
    // before gemm1 writes bufH).
    __half* bufB = (__half*)alloc((size_t)NN * 128 * 2);
    int* deg      = (int*)bufB;                                  // NN ints
    int* blocksum = (int*)((char*)bufB + (size_t)NN * 4);        // SCAN_BLOCKS ints
    int* row_start = (int*)alloc((size_t)(NN + 1) * 4);
    float* dinv = (float*)alloc((size_t)NN * 4);
    int* flagp  = (int*)alloc(256);
    int* csr    = (int*)alloc((size_t)NE * 4);
    __half* bufH = (__half*)alloc((size_t)NN * 128 * 2);
    int* bucketbuf = (int*)bufH;                                    // NBK*BCAP ints
    int* gcnt      = (int*)((char*)bufH + (size_t)NBK * BCAP * 4);  // NBK*16 ints
    __half* Wt1 = (__half*)alloc((size_t)128 * 128 * 2);
    __half* Wt2 = (__half*)alloc((size_t)128 * 128 * 2);
    __half* Wt3 = (__half*)alloc((size_t)64 * 128 * 2);
    int* scnt  = (int*)alloc(SBINS * 16 * 4);
    int* sbase = (int*)alloc(SBINS * 16 * 4);
    int* order = (int*)alloc((size_t)NN * 4);

    hipMemsetAsync(gcnt, 0, (size_t)NBK * 16 * 4, stream);
    hipMemsetAsync(scnt, 0, SBINS * 16 * 4, stream);
    detect_flag_kernel<<<1, 256, 0, stream>>>((const int*)eidx, flagp);
    bin_kernel<<<BIN_BLOCKS, 256, 0, stream>>>(eidx, flagp, gcnt, bucketbuf);
    hist_kernel<<<NBK, 256, 0, stream>>>(gcnt, bucketbuf, deg, dinv, scnt);
    scanA_kernel<<<SCAN_BLOCKS, 256, 0, stream>>>(deg, blocksum);
    scanC_kernel<<<SCAN_BLOCKS, 256, 0, stream>>>(deg, blocksum, row_start);
    csrfill_kernel<<<NBK, 256, 0, stream>>>(gcnt, bucketbuf, row_start, csr);
    sort_scan_kernel<<<1, 64, 0, stream>>>(scnt, sbase);
    order_kernel<<<NBK, 256, 0, stream>>>(deg, sbase, order);

    wt_kernel<<<(128 * 128 + 255) / 256, 256, 0, stream>>>(W1, Wt1, 128);
    wt_kernel<<<(128 * 128 + 255) / 256, 256, 0, stream>>>(W2, Wt2, 128);
    wt_kernel<<<(128 * 64 + 255) / 256, 256, 0, stream>>>(W3, Wt3, 64);

    const int GB = (NN + 63) / 64;   // 1563 gemm blocks
    // Layer 1 (reads fp32 x directly)
    mfma_gemm_kernel<128, float><<<GB, 256, 0, stream>>>(x, Wt1, dinv, bufH, NN);
    agg_kernel<128, true, __half><<<NN / 16, 256, 0, stream>>>(bufH, order, row_start, csr, dinv, b1, bufB);
    // Layer 2
    mfma_gemm_kernel<128, __half><<<GB, 256, 0, stream>>>(bufB, Wt2, dinv, bufH, NN);
    agg_kernel<128, true, __half><<<NN / 16, 256, 0, stream>>>(bufH, order, row_start, csr, dinv, b2, bufB);
    // Layer 3 (128 -> 64, no relu, fp32 out)
    mfma_gemm_kernel<64, __half><<<GB, 256, 0, stream>>>(bufB, Wt3, dinv, bufH, NN);
    agg_kernel<64, false, float><<<NN / 32, 256, 0, stream>>>(bufH, order, row_start, csr, dinv, b3, out);
}

// Round 9
// 398.765 us; speedup vs baseline: 2.5138x; 1.0654x over previous
//
#include <hip/hip_runtime.h>
#include <hip/hip_fp16.h>
#include <cstdint>
#include <cstddef>
#include <type_traits>

#define NN 100000
#define NE 1600000
#define SCAN_BLOCKS ((NN + 1023) / 1024)   // 98
#define NBK ((NN + 255) / 256)             // 391 dst-buckets of 256 nodes
#define BCAP 4608                          // mean 4092, std ~64 -> 8 sigma slack
#define EPB 4096                           // edges per bin block
#define BIN_BLOCKS ((NE + EPB - 1) / EPB)  // 391

using half8 = __attribute__((ext_vector_type(8))) _Float16;
using f32x4 = __attribute__((ext_vector_type(4))) float;

union F4H8 { float4 f4; __half2 h2[4]; };  // 16 B = 8 halves

__device__ __forceinline__ uint2 pack4half(float4 v) {
    __half2 a = __floats2half2_rn(v.x, v.y);
    __half2 b = __floats2half2_rn(v.z, v.w);
    uint2 r;
    r.x = *(unsigned int*)&a;
    r.y = *(unsigned int*)&b;
    return r;
}

// ---------------- edge-index detection ----------------
__global__ void detect_flag_kernel(const int* __restrict__ idx, int* __restrict__ flag) {
    __shared__ int cnt;
    if (threadIdx.x == 0) cnt = 0;
    __syncthreads();
    if (idx[2 * threadIdx.x + 1] == 0) atomicAdd(&cnt, 1);
    __syncthreads();
    if (threadIdx.x == 0) *flag = (cnt == (int)blockDim.x) ? 1 : 0;
}

// ---------------- CSR build ----------------
__global__ __launch_bounds__(256) void bin_kernel(const void* __restrict__ idx,
                                                  const int* __restrict__ flag,
                                                  int* __restrict__ gcnt,       // NBK, stride 16
                                                  int* __restrict__ bucketbuf) {
    __shared__ int cnt[NBK];
    __shared__ int gbase[NBK];
    int t = threadIdx.x;
    long long base = (long long)blockIdx.x * EPB;
    for (int i = t; i < NBK; i += 256) cnt[i] = 0;
    __syncthreads();
    bool is64 = (*flag != 0);
    int lpos[16], d16[16], s16[16];
#pragma unroll
    for (int j = 0; j < 16; j++) {
        long long e = base + j * 256 + t;
        lpos[j] = 0; d16[j] = 0; s16[j] = 0;
        if (e < NE) {
            int s_, d_;
            if (is64) { const long long* p = (const long long*)idx; s_ = (int)p[e]; d_ = (int)p[NE + e]; }
            else      { const int* p = (const int*)idx;             s_ = p[e];      d_ = p[NE + e]; }
            d16[j] = d_; s16[j] = s_;
            lpos[j] = atomicAdd(&cnt[d_ >> 8], 1);
        }
    }
    __syncthreads();
    for (int b = t; b < NBK; b += 256) {
        int c = cnt[b];
        gbase[b] = (c > 0) ? atomicAdd(&gcnt[b * 16], c) : 0;
    }
    __syncthreads();
#pragma unroll
    for (int j = 0; j < 16; j++) {
        long long e = base + j * 256 + t;
        if (e < NE) {
            int b = d16[j] >> 8;
            int pos = gbase[b] + lpos[j];
            if (pos < BCAP) bucketbuf[(size_t)b * BCAP + pos] = (s16[j] << 8) | (d16[j] & 255);
        }
    }
}

// Per-bucket LDS histogram -> deg + dinv (dense write, no global atomics).
__global__ __launch_bounds__(256) void hist_kernel(const int* __restrict__ gcnt,
                                                   const int* __restrict__ bucketbuf,
                                                   int* __restrict__ deg,
                                                   float* __restrict__ dinv) {
    __shared__ int cnt[256];
    int t = threadIdx.x, b = blockIdx.x;
    cnt[t] = 0;
    __syncthreads();
    int n = gcnt[b * 16]; if (n > BCAP) n = BCAP;
    for (int i = t; i < n; i += 256)
        atomicAdd(&cnt[bucketbuf[(size_t)b * BCAP + i] & 255], 1);
    __syncthreads();
    int node = b * 256 + t;
    if (node < NN) {
        int d = cnt[t];
        deg[node] = d;
        dinv[node] = rsqrtf((float)(d + 1));   // +1 self loop
    }
}

__global__ __launch_bounds__(256) void scanA_kernel(const int* __restrict__ deg,
                                                    int* __restrict__ blocksum) {
    __shared__ int red[256];
    int t = threadIdx.x;
    int base = blockIdx.x * 1024 + t * 4;
    int s = 0;
#pragma unroll
    for (int j = 0; j < 4; j++) { int i = base + j; if (i < NN) s += deg[i]; }
    red[t] = s;
    __syncthreads();
    for (int off = 128; off > 0; off >>= 1) {
        if (t < off) red[t] += red[t + off];
        __syncthreads();
    }
    if (t == 0) blocksum[blockIdx.x] = red[0];
}

__global__ __launch_bounds__(256) void scanC_kernel(const int* __restrict__ deg,
                                                    const int* __restrict__ blocksum,
                                                    int* __restrict__ row_start) {
    __shared__ int lds[256];
    __shared__ int boff_s;
    int t = threadIdx.x;
    int b = blockIdx.x;
    lds[t] = (t < b && t < SCAN_BLOCKS) ? blocksum[t] : 0;
    __syncthreads();
    for (int off = 128; off > 0; off >>= 1) {
        if (t < off) lds[t] += lds[t + off];
        __syncthreads();
    }
    if (t == 0) boff_s = lds[0];
    __syncthreads();
    int boff = boff_s;

    int base = b * 1024 + t * 4;
    int d[4]; int s = 0;
#pragma unroll
    for (int j = 0; j < 4; j++) { int i = base + j; d[j] = (i < NN) ? deg[i] : 0; s += d[j]; }
    __syncthreads();
    lds[t] = s;
    __syncthreads();
    for (int off = 1; off < 256; off <<= 1) {
        int u = (t >= off) ? lds[t - off] : 0;
        __syncthreads();
        lds[t] += u;
        __syncthreads();
    }
    int offr = boff + ((t == 0) ? 0 : lds[t - 1]);
#pragma unroll
    for (int j = 0; j < 4; j++) {
        int i = base + j;
        if (i < NN) { row_start[i] = offr; offr += d[j]; }
    }
    if (b == 0 && t == 0) row_start[NN] = NE;
}

__global__ __launch_bounds__(256) void csrfill_kernel(const int* __restrict__ gcnt,
                                                      const int* __restrict__ bucketbuf,
                                                      const int* __restrict__ row_start,
                                                      int* __restrict__ csr) {
    __shared__ int cur[256];
    int t = threadIdx.x, b = blockIdx.x;
    int node = b * 256 + t;
    cur[t] = (node < NN) ? row_start[node] : 0;
    __syncthreads();
    int n = gcnt[b * 16]; if (n > BCAP) n = BCAP;
    for (int i = t; i < n; i += 256) {
        int v = bucketbuf[(size_t)b * BCAP + i];
        int pos = atomicAdd(&cur[v & 255], 1);
        csr[pos] = v >> 8;
    }
}

// ---------------- conversions ----------------
__global__ void wt_kernel(const float* __restrict__ W, __half* __restrict__ Wt, int F) {
    int i = blockIdx.x * 256 + threadIdx.x;
    if (i >= 128 * F) return;
    int k = i / F, n = i % F;
    Wt[(size_t)n * 128 + k] = __float2half(W[i]);
}

// ---------------- MFMA GEMM (layer 1 only: fp32 A from global) ----------------
template <int F, typename AT>
__global__ __launch_bounds__(256) void mfma_gemm_kernel(const AT* __restrict__ A,
                                                        const __half* __restrict__ Wt,
                                                        const float* __restrict__ dinv,
                                                        __half* __restrict__ H, int N) {
    constexpr int K = 128;
    constexpr int NT = F / 16;
    constexpr int FP = F + 8;
    __shared__ __half hs[64 * FP];

    int wave = threadIdx.x >> 6;
    int lane = threadIdx.x & 63;
    int quad = lane >> 4;
    int l16  = lane & 15;
    int rowbase = blockIdx.x * 64 + wave * 16;
    int arow = rowbase + l16; if (arow >= N) arow = N - 1;

    half8 afrag[4];
    const AT* ap = A + (size_t)arow * K + quad * 8;
#pragma unroll
    for (int s = 0; s < 4; s++) {
        if constexpr (std::is_same<AT, float>::value) {
            float4 u0 = *(const float4*)(ap + s * 32);
            float4 u1 = *(const float4*)(ap + s * 32 + 4);
            half8 h;
            h[0] = (_Float16)u0.x; h[1] = (_Float16)u0.y;
            h[2] = (_Float16)u0.z; h[3] = (_Float16)u0.w;
            h[4] = (_Float16)u1.x; h[5] = (_Float16)u1.y;
            h[6] = (_Float16)u1.z; h[7] = (_Float16)u1.w;
            afrag[s] = h;
        } else {
            afrag[s] = *(const half8*)(ap + s * 32);
        }
    }

    f32x4 acc[NT];
#pragma unroll
    for (int t = 0; t < NT; t++) acc[t] = (f32x4){0.f, 0.f, 0.f, 0.f};

#pragma unroll
    for (int s = 0; s < 4; s++) {
#pragma unroll
        for (int t = 0; t < NT; t++) {
            half8 b = *(const half8*)(Wt + (size_t)(t * 16 + l16) * K + s * 32 + quad * 8);
            acc[t] = __builtin_amdgcn_mfma_f32_16x16x32_f16(afrag[s], b, acc[t], 0, 0, 0);
        }
    }

    float dv[4];
#pragma unroll
    for (int r = 0; r < 4; r++) {
        int grow = rowbase + quad * 4 + r;
        dv[r] = (grow < N) ? dinv[grow] : 0.f;
    }
#pragma unroll
    for (int t = 0; t < NT; t++) {
#pragma unroll
        for (int r = 0; r < 4; r++) {
            int lrow = wave * 16 + quad * 4 + r;
            hs[lrow * FP + t * 16 + l16] = __float2half(acc[t][r] * dv[r]);
        }
    }
    __syncthreads();
    constexpr int CHUNKS = 64 * F / 8;
    for (int i = threadIdx.x; i < CHUNKS; i += 256) {
        int row = i / (F / 8);
        int col8 = (i % (F / 8)) * 8;
        int grow = blockIdx.x * 64 + row;
        if (grow < N)
            *(uint4*)&H[(size_t)grow * F + col8] = *(const uint4*)&hs[row * FP + col8];
    }
}

// ---------------- fused agg + gemm ----------------
// Block = 64 nodes. Phase 1: gather-aggregate into LDS A-tile (fp16, +bias,
// relu). Phase 2: 4 waves MFMA A-tile @ Wt (L1-resident) -> next gather
// array Hout = fp16(dinv_row * (A @ W)). Kills the activation HBM round-trip.
template <int FO>
__global__ __launch_bounds__(256) void agg_gemm_kernel(const __half* __restrict__ Hs,  // [NN][128]
                                                       const int* __restrict__ rs,
                                                       const int* __restrict__ csr,
                                                       const float* __restrict__ dinv,
                                                       const float* __restrict__ bias, // [128]
                                                       const __half* __restrict__ Wt,  // [FO][128]
                                                       __half* __restrict__ Hout) {    // [NN][FO]
    constexpr int FI = 128;
    constexpr int FP = FI + 8;          // padded LDS stride (halves)
    constexpr int NT = FO / 16;
    __shared__ __half Alds[64 * FP];

    int tid = threadIdx.x;
    int nodebase = blockIdx.x * 64;

    // ---- Phase 1: aggregate 64 nodes (4 passes of 16 nodes) ----
#pragma unroll
    for (int pass = 0; pass < 4; pass++) {
        int lrow = pass * 16 + tid / 16;
        int node = nodebase + lrow;
        int q = (tid % 16) * 8;
        float acc[8];
        if (node < NN) {
            float dn = dinv[node];
            {   // self loop
                F4H8 u; u.f4 = *(const float4*)&Hs[(size_t)node * FI + q];
#pragma unroll
                for (int j = 0; j < 4; j++) {
                    float2 f = __half22float2(u.h2[j]);
                    acc[2 * j] = f.x; acc[2 * j + 1] = f.y;
                }
            }
            int e = rs[node];
            int e1 = rs[node + 1];
            for (; e + 8 <= e1; e += 8) {
                int s[8];
#pragma unroll
                for (int j = 0; j < 8; j++) s[j] = csr[e + j];
                F4H8 h[8];
#pragma unroll
                for (int j = 0; j < 8; j++) h[j].f4 = *(const float4*)&Hs[(size_t)s[j] * FI + q];
#pragma unroll
                for (int j = 0; j < 8; j++) {
#pragma unroll
                    for (int k = 0; k < 4; k++) {
                        float2 f = __half22float2(h[j].h2[k]);
                        acc[2 * k] += f.x; acc[2 * k + 1] += f.y;
                    }
                }
            }
            for (; e < e1; e++) {
                int s = csr[e];
                F4H8 u; u.f4 = *(const float4*)&Hs[(size_t)s * FI + q];
#pragma unroll
                for (int k = 0; k < 4; k++) {
                    float2 f = __half22float2(u.h2[k]);
                    acc[2 * k] += f.x; acc[2 * k + 1] += f.y;
                }
            }
#pragma unroll
            for (int j = 0; j < 8; j++)
                acc[j] = fmaxf(dn * acc[j] + bias[q + j], 0.f);  // bias + relu
        } else {
#pragma unroll
            for (int j = 0; j < 8; j++) acc[j] = 0.f;
        }
        uint4 p;
        uint2 a = pack4half(make_float4(acc[0], acc[1], acc[2], acc[3]));
        uint2 b = pack4half(make_float4(acc[4], acc[5], acc[6], acc[7]));
        p.x = a.x; p.y = a.y; p.z = b.x; p.w = b.y;
        *(uint4*)&Alds[lrow * FP + q] = p;
    }
    __syncthreads();

    // ---- Phase 2: MFMA A-tile @ Wt ----
    int wave = tid >> 6;
    int lane = tid & 63;
    int quad = lane >> 4;
    int l16  = lane & 15;
    int rowbase = nodebase + wave * 16;

    half8 afrag[4];
#pragma unroll
    for (int s = 0; s < 4; s++)
        afrag[s] = *(const half8*)&Alds[(wave * 16 + l16) * FP + s * 32 + quad * 8];

    f32x4 acc[NT];
#pragma unroll
    for (int t = 0; t < NT; t++) acc[t] = (f32x4){0.f, 0.f, 0.f, 0.f};
#pragma unroll
    for (int s = 0; s < 4; s++) {
#pragma unroll
        for (int t = 0; t < NT; t++) {
            half8 b = *(const half8*)(Wt + (size_t)(t * 16 + l16) * FI + s * 32 + quad * 8);
            acc[t] = __builtin_amdgcn_mfma_f32_16x16x32_f16(afrag[s], b, acc[t], 0, 0, 0);
        }
    }

    // C/D: col=l16, row=quad*4+r. Scale by dinv (pre-scale for next gather),
    // stash in own wave's LDS rows (only this wave read them), then store.
    float dv[4];
#pragma unroll
    for (int r = 0; r < 4; r++) {
        int grow = rowbase + quad * 4 + r;
        dv[r] = (grow < NN) ? dinv[grow] : 0.f;
    }
#pragma unroll
    for (int t = 0; t < NT; t++) {
#pragma unroll
        for (int r = 0; r < 4; r++) {
            int lrow = wave * 16 + quad * 4 + r;
            Alds[lrow * FP + t * 16 + l16] = __float2half(acc[t][r] * dv[r]);
        }
    }
    __syncthreads();
    constexpr int CHUNKS = 64 * FO / 8;
    for (int i = tid; i < CHUNKS; i += 256) {
        int row = i / (FO / 8);
        int col8 = (i % (FO / 8)) * 8;
        int grow = nodebase + row;
        if (grow < NN)
            *(uint4*)&Hout[(size_t)grow * FO + col8] = *(const uint4*)&Alds[row * FP + col8];
    }
}

// ---------------- final aggregation (F=64, fp32 out) ----------------
template <int F>
__global__ __launch_bounds__(256) void agg_kernel(const __half* __restrict__ Hs,
                                                  const int* __restrict__ rs,
                                                  const int* __restrict__ csr,
                                                  const float* __restrict__ dinv,
                                                  const float* __restrict__ bias,
                                                  float* __restrict__ OUT) {
    constexpr int CQ = F / 8;
    constexpr int NPB = 256 / CQ;
    int node = blockIdx.x * NPB + threadIdx.x / CQ;
    int q = (threadIdx.x % CQ) * 8;
    if (node >= NN) return;
    float dn = dinv[node];
    float acc[8];
    {
        F4H8 u; u.f4 = *(const float4*)&Hs[(size_t)node * F + q];
#pragma unroll
        for (int j = 0; j < 4; j++) {
            float2 f = __half22float2(u.h2[j]);
            acc[2 * j] = f.x; acc[2 * j + 1] = f.y;
        }
    }
    int e = rs[node];
    int e1 = rs[node + 1];
    for (; e + 8 <= e1; e += 8) {
        int s[8];
#pragma unroll
        for (int j = 0; j < 8; j++) s[j] = csr[e + j];
        F4H8 h[8];
#pragma unroll
        for (int j = 0; j < 8; j++) h[j].f4 = *(const float4*)&Hs[(size_t)s[j] * F + q];
#pragma unroll
        for (int j = 0; j < 8; j++) {
#pragma unroll
            for (int k = 0; k < 4; k++) {
                float2 f = __half22float2(h[j].h2[k]);
                acc[2 * k] += f.x; acc[2 * k + 1] += f.y;
            }
        }
    }
    for (; e < e1; e++) {
        int s = csr[e];
        F4H8 u; u.f4 = *(const float4*)&Hs[(size_t)s * F + q];
#pragma unroll
        for (int k = 0; k < 4; k++) {
            float2 f = __half22float2(u.h2[k]);
            acc[2 * k] += f.x; acc[2 * k + 1] += f.y;
        }
    }
    float4 o0 = make_float4(dn * acc[0] + bias[q],     dn * acc[1] + bias[q + 1],
                            dn * acc[2] + bias[q + 2], dn * acc[3] + bias[q + 3]);
    float4 o1 = make_float4(dn * acc[4] + bias[q + 4], dn * acc[5] + bias[q + 5],
                            dn * acc[6] + bias[q + 6], dn * acc[7] + bias[q + 7]);
    *(float4*)&OUT[(size_t)node * F + q]     = o0;
    *(float4*)&OUT[(size_t)node * F + q + 4] = o1;
}

extern "C" void kernel_launch(void* const* d_in, const int* in_sizes, int n_in,
                              void* d_out, int out_size, void* d_ws, size_t ws_size,
                              hipStream_t stream) {
    const float* x  = (const float*)d_in[0];
    const void* eidx = d_in[1];
    const float* W1 = (const float*)d_in[2];
    const float* b1 = (const float*)d_in[3];
    const float* W2 = (const float*)d_in[4];
    const float* b2 = (const float*)d_in[5];
    const float* W3 = (const float*)d_in[6];
    const float* b3 = (const float*)d_in[7];
    float* out = (float*)d_out;

    char* ws = (char*)d_ws;
    size_t off = 0;
    auto alloc = [&](size_t bytes) -> void* {
        void* p = ws + off;
        off += (bytes + 255) & ~(size_t)255;
        return p;
    };
    // bufA (Hs1, then Hs3) overlays bucketbuf/gcnt (dead before gemm1 writes);
    // bufC (Hs2) overlays deg/blocksum (dead before fused1 writes).
    __half* bufA = (__half*)alloc((size_t)NN * 128 * 2);
    int* bucketbuf = (int*)bufA;                                    // NBK*BCAP ints
    int* gcnt      = (int*)((char*)bufA + (size_t)NBK * BCAP * 4);  // NBK*16 ints
    __half* bufC = (__half*)alloc((size_t)NN * 128 * 2);
    int* deg      = (int*)bufC;                                  // NN ints
    int* blocksum = (int*)((char*)bufC + (size_t)NN * 4);        // SCAN_BLOCKS ints
    int* row_start = (int*)alloc((size_t)(NN + 1) * 4);
    float* dinv = (float*)alloc((size_t)NN * 4);
    int* flagp  = (int*)alloc(256);
    int* csr    = (int*)alloc((size_t)NE * 4);
    __half* Wt1 = (__half*)alloc((size_t)128 * 128 * 2);
    __half* Wt2 = (__half*)alloc((size_t)128 * 128 * 2);
    __half* Wt3 = (__half*)alloc((size_t)64 * 128 * 2);

    hipMemsetAsync(gcnt, 0, (size_t)NBK * 16 * 4, stream);
    detect_flag_kernel<<<1, 256, 0, stream>>>((const int*)eidx, flagp);
    bin_kernel<<<BIN_BLOCKS, 256, 0, stream>>>(eidx, flagp, gcnt, bucketbuf);
    hist_kernel<<<NBK, 256, 0, stream>>>(gcnt, bucketbuf, deg, dinv);
    scanA_kernel<<<SCAN_BLOCKS, 256, 0, stream>>>(deg, blocksum);
    scanC_kernel<<<SCAN_BLOCKS, 256, 0, stream>>>(deg, blocksum, row_start);
    csrfill_kernel<<<NBK, 256, 0, stream>>>(gcnt, bucketbuf, row_start, csr);

    wt_kernel<<<(128 * 128 + 255) / 256, 256, 0, stream>>>(W1, Wt1, 128);
    wt_kernel<<<(128 * 128 + 255) / 256, 256, 0, stream>>>(W2, Wt2, 128);
    wt_kernel<<<(128 * 64 + 255) / 256, 256, 0, stream>>>(W3, Wt3, 64);

    const int GB = (NN + 63) / 64;   // 1563 blocks
    // Layer 1 GEMM: Hs1 = fp16(dinv * (x @ W1))
    mfma_gemm_kernel<128, float><<<GB, 256, 0, stream>>>(x, Wt1, dinv, bufA, NN);
    // Fused agg1 + gemm2: Hs2 = fp16(dinv * (relu(dn*(gather Hs1)+b1) @ W2))
    agg_gemm_kernel<128><<<GB, 256, 0, stream>>>(bufA, row_start, csr, dinv, b1, Wt2, bufC);
    // Fused agg2 + gemm3: Hs3 = fp16(dinv * (relu(dn*(gather Hs2)+b2) @ W3))
    agg_gemm_kernel<64><<<GB, 256, 0, stream>>>(bufC, row_start, csr, dinv, b2, Wt3, bufA);
    // Final agg (F=64, fp32 out, no relu)
    agg_kernel<64><<<NN / 32, 256, 0, stream>>>(bufA, row_start, csr, dinv, b3, out);
}

// Round 10
// 376.237 us; speedup vs baseline: 2.6644x; 1.0599x over previous
//
#include <hip/hip_runtime.h>
#include <hip/hip_fp16.h>
#include <cstdint>
#include <cstddef>
#include <type_traits>

#define NN 100000
#define NE 1600000
#define SCAN_BLOCKS ((NN + 1023) / 1024)   // 98
#define NBK ((NN + 255) / 256)             // 391 dst-buckets of 256 nodes
#define BCAP 4608                          // mean 4092, std ~64 -> 8 sigma slack
#define EPB 4096                           // edges per bin block
#define BIN_BLOCKS ((NE + EPB - 1) / EPB)  // 391

using half8 = __attribute__((ext_vector_type(8))) _Float16;
using f32x4 = __attribute__((ext_vector_type(4))) float;

union F4H8 { float4 f4; __half2 h2[4]; };  // 16 B = 8 halves

__device__ __forceinline__ uint2 pack4half(float4 v) {
    __half2 a = __floats2half2_rn(v.x, v.y);
    __half2 b = __floats2half2_rn(v.z, v.w);
    uint2 r;
    r.x = *(unsigned int*)&a;
    r.y = *(unsigned int*)&b;
    return r;
}

// ---------------- edge-index detection ----------------
__global__ void detect_flag_kernel(const int* __restrict__ idx, int* __restrict__ flag) {
    __shared__ int cnt;
    if (threadIdx.x == 0) cnt = 0;
    __syncthreads();
    if (idx[2 * threadIdx.x + 1] == 0) atomicAdd(&cnt, 1);
    __syncthreads();
    if (threadIdx.x == 0) *flag = (cnt == (int)blockDim.x) ? 1 : 0;
}

// ---------------- CSR build ----------------
__global__ __launch_bounds__(256) void bin_kernel(const void* __restrict__ idx,
                                                  const int* __restrict__ flag,
                                                  int* __restrict__ gcnt,       // NBK, stride 16
                                                  int* __restrict__ bucketbuf) {
    __shared__ int cnt[NBK];
    __shared__ int gbase[NBK];
    int t = threadIdx.x;
    long long base = (long long)blockIdx.x * EPB;
    for (int i = t; i < NBK; i += 256) cnt[i] = 0;
    __syncthreads();
    bool is64 = (*flag != 0);
    int lpos[16], d16[16], s16[16];
#pragma unroll
    for (int j = 0; j < 16; j++) {
        long long e = base + j * 256 + t;
        lpos[j] = 0; d16[j] = 0; s16[j] = 0;
        if (e < NE) {
            int s_, d_;
            if (is64) { const long long* p = (const long long*)idx; s_ = (int)p[e]; d_ = (int)p[NE + e]; }
            else      { const int* p = (const int*)idx;             s_ = p[e];      d_ = p[NE + e]; }
            d16[j] = d_; s16[j] = s_;
            lpos[j] = atomicAdd(&cnt[d_ >> 8], 1);
        }
    }
    __syncthreads();
    for (int b = t; b < NBK; b += 256) {
        int c = cnt[b];
        gbase[b] = (c > 0) ? atomicAdd(&gcnt[b * 16], c) : 0;
    }
    __syncthreads();
#pragma unroll
    for (int j = 0; j < 16; j++) {
        long long e = base + j * 256 + t;
        if (e < NE) {
            int b = d16[j] >> 8;
            int pos = gbase[b] + lpos[j];
            if (pos < BCAP) bucketbuf[(size_t)b * BCAP + pos] = (s16[j] << 8) | (d16[j] & 255);
        }
    }
}

// Per-bucket LDS histogram -> deg + dinv (dense write, no global atomics).
__global__ __launch_bounds__(256) void hist_kernel(const int* __restrict__ gcnt,
                                                   const int* __restrict__ bucketbuf,
                                                   int* __restrict__ deg,
                                                   float* __restrict__ dinv) {
    __shared__ int cnt[256];
    int t = threadIdx.x, b = blockIdx.x;
    cnt[t] = 0;
    __syncthreads();
    int n = gcnt[b * 16]; if (n > BCAP) n = BCAP;
    for (int i = t; i < n; i += 256)
        atomicAdd(&cnt[bucketbuf[(size_t)b * BCAP + i] & 255], 1);
    __syncthreads();
    int node = b * 256 + t;
    if (node < NN) {
        int d = cnt[t];
        deg[node] = d;
        dinv[node] = rsqrtf((float)(d + 1));   // +1 self loop
    }
}

__global__ __launch_bounds__(256) void scanA_kernel(const int* __restrict__ deg,
                                                    int* __restrict__ blocksum) {
    __shared__ int red[256];
    int t = threadIdx.x;
    int base = blockIdx.x * 1024 + t * 4;
    int s = 0;
#pragma unroll
    for (int j = 0; j < 4; j++) { int i = base + j; if (i < NN) s += deg[i]; }
    red[t] = s;
    __syncthreads();
    for (int off = 128; off > 0; off >>= 1) {
        if (t < off) red[t] += red[t + off];
        __syncthreads();
    }
    if (t == 0) blocksum[blockIdx.x] = red[0];
}

__global__ __launch_bounds__(256) void scanC_kernel(const int* __restrict__ deg,
                                                    const int* __restrict__ blocksum,
                                                    int* __restrict__ row_start) {
    __shared__ int lds[256];
    __shared__ int boff_s;
    int t = threadIdx.x;
    int b = blockIdx.x;
    lds[t] = (t < b && t < SCAN_BLOCKS) ? blocksum[t] : 0;
    __syncthreads();
    for (int off = 128; off > 0; off >>= 1) {
        if (t < off) lds[t] += lds[t + off];
        __syncthreads();
    }
    if (t == 0) boff_s = lds[0];
    __syncthreads();
    int boff = boff_s;

    int base = b * 1024 + t * 4;
    int d[4]; int s = 0;
#pragma unroll
    for (int j = 0; j < 4; j++) { int i = base + j; d[j] = (i < NN) ? deg[i] : 0; s += d[j]; }
    __syncthreads();
    lds[t] = s;
    __syncthreads();
    for (int off = 1; off < 256; off <<= 1) {
        int u = (t >= off) ? lds[t - off] : 0;
        __syncthreads();
        lds[t] += u;
        __syncthreads();
    }
    int offr = boff + ((t == 0) ? 0 : lds[t - 1]);
#pragma unroll
    for (int j = 0; j < 4; j++) {
        int i = base + j;
        if (i < NN) { row_start[i] = offr; offr += d[j]; }
    }
    if (b == 0 && t == 0) row_start[NN] = NE;
}

__global__ __launch_bounds__(256) void csrfill_kernel(const int* __restrict__ gcnt,
                                                      const int* __restrict__ bucketbuf,
                                                      const int* __restrict__ row_start,
                                                      int* __restrict__ csr) {
    __shared__ int cur[256];
    int t = threadIdx.x, b = blockIdx.x;
    int node = b * 256 + t;
    cur[t] = (node < NN) ? row_start[node] : 0;
    __syncthreads();
    int n = gcnt[b * 16]; if (n > BCAP) n = BCAP;
    for (int i = t; i < n; i += 256) {
        int v = bucketbuf[(size_t)b * BCAP + i];
        int pos = atomicAdd(&cur[v & 255], 1);
        csr[pos] = v >> 8;
    }
}

// ---------------- conversions ----------------
__global__ void wt_kernel(const float* __restrict__ W, __half* __restrict__ Wt, int F) {
    int i = blockIdx.x * 256 + threadIdx.x;
    if (i >= 128 * F) return;
    int k = i / F, n = i % F;
    Wt[(size_t)n * 128 + k] = __float2half(W[i]);
}

// ---------------- MFMA GEMM (layer 1 only: fp32 A from global) ----------------
template <int F, typename AT>
__global__ __launch_bounds__(256) void mfma_gemm_kernel(const AT* __restrict__ A,
                                                        const __half* __restrict__ Wt,
                                                        const float* __restrict__ dinv,
                                                        __half* __restrict__ H, int N) {
    constexpr int K = 128;
    constexpr int NT = F / 16;
    constexpr int FP = F + 8;
    __shared__ __half hs[64 * FP];

    int wave = threadIdx.x >> 6;
    int lane = threadIdx.x & 63;
    int quad = lane >> 4;
    int l16  = lane & 15;
    int rowbase = blockIdx.x * 64 + wave * 16;
    int arow = rowbase + l16; if (arow >= N) arow = N - 1;

    half8 afrag[4];
    const AT* ap = A + (size_t)arow * K + quad * 8;
#pragma unroll
    for (int s = 0; s < 4; s++) {
        if constexpr (std::is_same<AT, float>::value) {
            float4 u0 = *(const float4*)(ap + s * 32);
            float4 u1 = *(const float4*)(ap + s * 32 + 4);
            half8 h;
            h[0] = (_Float16)u0.x; h[1] = (_Float16)u0.y;
            h[2] = (_Float16)u0.z; h[3] = (_Float16)u0.w;
            h[4] = (_Float16)u1.x; h[5] = (_Float16)u1.y;
            h[6] = (_Float16)u1.z; h[7] = (_Float16)u1.w;
            afrag[s] = h;
        } else {
            afrag[s] = *(const half8*)(ap + s * 32);
        }
    }

    f32x4 acc[NT];
#pragma unroll
    for (int t = 0; t < NT; t++) acc[t] = (f32x4){0.f, 0.f, 0.f, 0.f};

#pragma unroll
    for (int s = 0; s < 4; s++) {
#pragma unroll
        for (int t = 0; t < NT; t++) {
            half8 b = *(const half8*)(Wt + (size_t)(t * 16 + l16) * K + s * 32 + quad * 8);
            acc[t] = __builtin_amdgcn_mfma_f32_16x16x32_f16(afrag[s], b, acc[t], 0, 0, 0);
        }
    }

    float dv[4];
#pragma unroll
    for (int r = 0; r < 4; r++) {
        int grow = rowbase + quad * 4 + r;
        dv[r] = (grow < N) ? dinv[grow] : 0.f;
    }
#pragma unroll
    for (int t = 0; t < NT; t++) {
#pragma unroll
        for (int r = 0; r < 4; r++) {
            int lrow = wave * 16 + quad * 4 + r;
            hs[lrow * FP + t * 16 + l16] = __float2half(acc[t][r] * dv[r]);
        }
    }
    __syncthreads();
    constexpr int CHUNKS = 64 * F / 8;
    for (int i = threadIdx.x; i < CHUNKS; i += 256) {
        int row = i / (F / 8);
        int col8 = (i % (F / 8)) * 8;
        int grow = blockIdx.x * 64 + row;
        if (grow < N)
            *(uint4*)&H[(size_t)grow * F + col8] = *(const uint4*)&hs[row * FP + col8];
    }
}

// ---------------- fused agg + gemm (16 nodes/block, R10) ----------------
// Phase 1 is the standalone agg structure verbatim (16 threads/node, 16
// nodes/block, grid 6250 -- preserves the occupancy/queue shape that
// standalone agg achieved 3.6 TB/s with; the R9 64-node version starved the
// dispatch queue). Phase 2: 4 waves MFMA the 16x128 LDS A-tile against
// L1-resident Wt, each wave covering FO/4 output cols; C routed through the
// same LDS for coalesced stores. 6250*16 == NN exactly: no row bounds checks.
template <int FO>
__global__ __launch_bounds__(256) void agg_gemm_kernel(const __half* __restrict__ Hs,  // [NN][128]
                                                       const int* __restrict__ rs,
                                                       const int* __restrict__ csr,
                                                       const float* __restrict__ dinv,
                                                       const float* __restrict__ bias, // [128] fp32
                                                       const __half* __restrict__ Wt,  // [FO][128]
                                                       __half* __restrict__ Hout) {    // [NN][FO]
    constexpr int FI = 128;
    constexpr int FP = FI + 8;          // 136: A-tile stride (halves)
    constexpr int FPO = FO + 8;         // C-tile stride
    constexpr int NT4 = FO / 64;        // col-tiles per wave (2 or 1)
    __shared__ __half Alds[16 * FP];    // 4.25 KB

    int tid = threadIdx.x;
    int nodebase = blockIdx.x * 16;
    int lrow = tid / 16;
    int node = nodebase + lrow;
    int q = (tid % 16) * 8;

    // ---- Phase 1: gather-aggregate ----
    float dn = dinv[node];
    float acc[8];
    {   // self loop
        F4H8 u; u.f4 = *(const float4*)&Hs[(size_t)node * FI + q];
#pragma unroll
        for (int j = 0; j < 4; j++) {
            float2 f = __half22float2(u.h2[j]);
            acc[2 * j] = f.x; acc[2 * j + 1] = f.y;
        }
    }
    int e = rs[node];
    int e1 = rs[node + 1];
    for (; e + 8 <= e1; e += 8) {
        int s[8];
#pragma unroll
        for (int j = 0; j < 8; j++) s[j] = csr[e + j];
        F4H8 h[8];
#pragma unroll
        for (int j = 0; j < 8; j++) h[j].f4 = *(const float4*)&Hs[(size_t)s[j] * FI + q];
#pragma unroll
        for (int j = 0; j < 8; j++) {
#pragma unroll
            for (int k = 0; k < 4; k++) {
                float2 f = __half22float2(h[j].h2[k]);
                acc[2 * k] += f.x; acc[2 * k + 1] += f.y;
            }
        }
    }
    for (; e < e1; e++) {
        int s = csr[e];
        F4H8 u; u.f4 = *(const float4*)&Hs[(size_t)s * FI + q];
#pragma unroll
        for (int k = 0; k < 4; k++) {
            float2 f = __half22float2(u.h2[k]);
            acc[2 * k] += f.x; acc[2 * k + 1] += f.y;
        }
    }
    float4 b0 = *(const float4*)&bias[q];
    float4 b1 = *(const float4*)&bias[q + 4];
    float o[8];
    o[0] = fmaxf(dn * acc[0] + b0.x, 0.f); o[1] = fmaxf(dn * acc[1] + b0.y, 0.f);
    o[2] = fmaxf(dn * acc[2] + b0.z, 0.f); o[3] = fmaxf(dn * acc[3] + b0.w, 0.f);
    o[4] = fmaxf(dn * acc[4] + b1.x, 0.f); o[5] = fmaxf(dn * acc[5] + b1.y, 0.f);
    o[6] = fmaxf(dn * acc[6] + b1.z, 0.f); o[7] = fmaxf(dn * acc[7] + b1.w, 0.f);
    {
        uint4 p;
        uint2 a = pack4half(make_float4(o[0], o[1], o[2], o[3]));
        uint2 b = pack4half(make_float4(o[4], o[5], o[6], o[7]));
        p.x = a.x; p.y = a.y; p.z = b.x; p.w = b.y;
        *(uint4*)&Alds[lrow * FP + q] = p;
    }
    __syncthreads();

    // ---- Phase 2: MFMA A-tile @ Wt; wave w covers col-tiles [w*NT4, (w+1)*NT4) ----
    int wave = tid >> 6;
    int lane = tid & 63;
    int quad = lane >> 4;
    int l16  = lane & 15;

    half8 afrag[4];
#pragma unroll
    for (int s = 0; s < 4; s++)
        afrag[s] = *(const half8*)&Alds[l16 * FP + s * 32 + quad * 8];

    f32x4 cacc[NT4];
#pragma unroll
    for (int t = 0; t < NT4; t++) cacc[t] = (f32x4){0.f, 0.f, 0.f, 0.f};
#pragma unroll
    for (int s = 0; s < 4; s++) {
#pragma unroll
        for (int t = 0; t < NT4; t++) {
            int tile = wave * NT4 + t;
            half8 b = *(const half8*)(Wt + (size_t)(tile * 16 + l16) * FI + s * 32 + quad * 8);
            cacc[t] = __builtin_amdgcn_mfma_f32_16x16x32_f16(afrag[s], b, cacc[t], 0, 0, 0);
        }
    }
    __syncthreads();   // all A reads done; reuse Alds for C

    // C/D: col=l16, row=quad*4+r; scale rows by dinv (pre-scale for next gather)
    float dv[4];
#pragma unroll
    for (int r = 0; r < 4; r++) dv[r] = dinv[nodebase + quad * 4 + r];
#pragma unroll
    for (int t = 0; t < NT4; t++) {
        int colb = (wave * NT4 + t) * 16 + l16;
#pragma unroll
        for (int r = 0; r < 4; r++)
            Alds[(quad * 4 + r) * FPO + colb] = __float2half(cacc[t][r] * dv[r]);
    }
    __syncthreads();
    constexpr int CHUNKS = 16 * FO / 8;
    for (int i = tid; i < CHUNKS; i += 256) {
        int row = i / (FO / 8);
        int col8 = (i % (FO / 8)) * 8;
        *(uint4*)&Hout[(size_t)(nodebase + row) * FO + col8] = *(const uint4*)&Alds[row * FPO + col8];
    }
}

// ---------------- final aggregation (F=64, fp32 out) ----------------
template <int F>
__global__ __launch_bounds__(256) void agg_kernel(const __half* __restrict__ Hs,
                                                  const int* __restrict__ rs,
                                                  const int* __restrict__ csr,
                                                  const float* __restrict__ dinv,
                                                  const float* __restrict__ bias,
                                                  float* __restrict__ OUT) {
    constexpr int CQ = F / 8;
    constexpr int NPB = 256 / CQ;
    int node = blockIdx.x * NPB + threadIdx.x / CQ;
    int q = (threadIdx.x % CQ) * 8;
    if (node >= NN) return;
    float dn = dinv[node];
    float acc[8];
    {
        F4H8 u; u.f4 = *(const float4*)&Hs[(size_t)node * F + q];
#pragma unroll
        for (int j = 0; j < 4; j++) {
            float2 f = __half22float2(u.h2[j]);
            acc[2 * j] = f.x; acc[2 * j + 1] = f.y;
        }
    }
    int e = rs[node];
    int e1 = rs[node + 1];
    for (; e + 8 <= e1; e += 8) {
        int s[8];
#pragma unroll
        for (int j = 0; j < 8; j++) s[j] = csr[e + j];
        F4H8 h[8];
#pragma unroll
        for (int j = 0; j < 8; j++) h[j].f4 = *(const float4*)&Hs[(size_t)s[j] * F + q];
#pragma unroll
        for (int j = 0; j < 8; j++) {
#pragma unroll
            for (int k = 0; k < 4; k++) {
                float2 f = __half22float2(h[j].h2[k]);
                acc[2 * k] += f.x; acc[2 * k + 1] += f.y;
            }
        }
    }
    for (; e < e1; e++) {
        int s = csr[e];
        F4H8 u; u.f4 = *(const float4*)&Hs[(size_t)s * F + q];
#pragma unroll
        for (int k = 0; k < 4; k++) {
            float2 f = __half22float2(u.h2[k]);
            acc[2 * k] += f.x; acc[2 * k + 1] += f.y;
        }
    }
    float4 o0 = make_float4(dn * acc[0] + bias[q],     dn * acc[1] + bias[q + 1],
                            dn * acc[2] + bias[q + 2], dn * acc[3] + bias[q + 3]);
    float4 o1 = make_float4(dn * acc[4] + bias[q + 4], dn * acc[5] + bias[q + 5],
                            dn * acc[6] + bias[q + 6], dn * acc[7] + bias[q + 7]);
    *(float4*)&OUT[(size_t)node * F + q]     = o0;
    *(float4*)&OUT[(size_t)node * F + q + 4] = o1;
}

extern "C" void kernel_launch(void* const* d_in, const int* in_sizes, int n_in,
                              void* d_out, int out_size, void* d_ws, size_t ws_size,
                              hipStream_t stream) {
    const float* x  = (const float*)d_in[0];
    const void* eidx = d_in[1];
    const float* W1 = (const float*)d_in[2];
    const float* b1 = (const float*)d_in[3];
    const float* W2 = (const float*)d_in[4];
    const float* b2 = (const float*)d_in[5];
    const float* W3 = (const float*)d_in[6];
    const float* b3 = (const float*)d_in[7];
    float* out = (float*)d_out;

    char* ws = (char*)d_ws;
    size_t off = 0;
    auto alloc = [&](size_t bytes) -> void* {
        void* p = ws + off;
        off += (bytes + 255) & ~(size_t)255;
        return p;
    };
    // bufA (Hs1, then Hs3) overlays bucketbuf/gcnt (dead before gemm1 writes);
    // bufC (Hs2) overlays deg/blocksum (dead before fused1 writes).
    __half* bufA = (__half*)alloc((size_t)NN * 128 * 2);
    int* bucketbuf = (int*)bufA;                                    // NBK*BCAP ints
    int* gcnt      = (int*)((char*)bufA + (size_t)NBK * BCAP * 4);  // NBK*16 ints
    __half* bufC = (__half*)alloc((size_t)NN * 128 * 2);
    int* deg      = (int*)bufC;                                  // NN ints
    int* blocksum = (int*)((char*)bufC + (size_t)NN * 4);        // SCAN_BLOCKS ints
    int* row_start = (int*)alloc((size_t)(NN + 1) * 4);
    float* dinv = (float*)alloc((size_t)NN * 4);
    int* flagp  = (int*)alloc(256);
    int* csr    = (int*)alloc((size_t)NE * 4);
    __half* Wt1 = (__half*)alloc((size_t)128 * 128 * 2);
    __half* Wt2 = (__half*)alloc((size_t)128 * 128 * 2);
    __half* Wt3 = (__half*)alloc((size_t)64 * 128 * 2);

    hipMemsetAsync(gcnt, 0, (size_t)NBK * 16 * 4, stream);
    detect_flag_kernel<<<1, 256, 0, stream>>>((const int*)eidx, flagp);
    bin_kernel<<<BIN_BLOCKS, 256, 0, stream>>>(eidx, flagp, gcnt, bucketbuf);
    hist_kernel<<<NBK, 256, 0, stream>>>(gcnt, bucketbuf, deg, dinv);
    scanA_kernel<<<SCAN_BLOCKS, 256, 0, stream>>>(deg, blocksum);
    scanC_kernel<<<SCAN_BLOCKS, 256, 0, stream>>>(deg, blocksum, row_start);
    csrfill_kernel<<<NBK, 256, 0, stream>>>(gcnt, bucketbuf, row_start, csr);

    wt_kernel<<<(128 * 128 + 255) / 256, 256, 0, stream>>>(W1, Wt1, 128);
    wt_kernel<<<(128 * 128 + 255) / 256, 256, 0, stream>>>(W2, Wt2, 128);
    wt_kernel<<<(128 * 64 + 255) / 256, 256, 0, stream>>>(W3, Wt3, 64);

    const int GB = (NN + 63) / 64;   // 1563 blocks (gemm1 only)
    // Layer 1 GEMM: Hs1 = fp16(dinv * (x @ W1))
    mfma_gemm_kernel<128, float><<<GB, 256, 0, stream>>>(x, Wt1, dinv, bufA, NN);
    // Fused agg1 + gemm2 (16 nodes/block, 6250 blocks)
    agg_gemm_kernel<128><<<NN / 16, 256, 0, stream>>>(bufA, row_start, csr, dinv, b1, Wt2, bufC);
    // Fused agg2 + gemm3
    agg_gemm_kernel<64><<<NN / 16, 256, 0, stream>>>(bufC, row_start, csr, dinv, b2, Wt3, bufA);
    // Final agg (F=64, fp32 out, no relu)
    agg_kernel<64><<<NN / 32, 256, 0, stream>>>(bufA, row_start, csr, dinv, b3, out);
}